// Round 2
// baseline (265.354 us; speedup 1.0000x reference)
//
#include <hip/hip_runtime.h>
#include <hip/hip_bf16.h>

// Problem: B=8, C=DIM=64, H=W=64 -> pooled 32x32 (N=1024 tokens), 16 heads x d=4.
// ws layout (floats): t[524288] | idx[524288 ints] | q[524288] | k[524288] | v[524288]
//                     | o[524288] (softmax numerator, atomically accumulated)
//                     | l[131072] (softmax denominator per (b,n,h))
// q/k/v layout: (B, H=16, N=1024, D=4) contiguous -> per (b,h) a 4096-float slab.

// ---------------- Kernel A: 2x2 maxpool + argmax, + zero-init o/l ----------------
__global__ __launch_bounds__(256) void pool_kernel(const float* __restrict__ x,
                                                   float* __restrict__ t,
                                                   int* __restrict__ idx,
                                                   float* __restrict__ o,
                                                   float* __restrict__ l) {
    int g = blockIdx.x * 256 + threadIdx.x;            // covers 8*64*32*32 = 524288
    int wp = g & 31, hp = (g >> 5) & 31, c = (g >> 10) & 63, b = g >> 16;
    const float* px = x + (((b * 64 + c) * 64 + 2 * hp) * 64 + 2 * wp);
    float2 r0 = *(const float2*)px;
    float2 r1 = *(const float2*)(px + 64);
    float best = r0.x; int bi = 0;                      // first-max semantics (strict >)
    if (r0.y > best) { best = r0.y; bi = 1; }
    if (r1.x > best) { best = r1.x; bi = 2; }
    if (r1.y > best) { best = r1.y; bi = 3; }
    int n = hp * 32 + wp;
    t[(b * 1024 + n) * 64 + c] = best;
    idx[g] = bi;                                        // layout (b,c,hp,wp)
    o[g] = 0.f;                                         // zero-init attn numerator
    if (g < 131072) l[g] = 0.f;                         // zero-init attn denominator
}

// ---------------- Kernel B: qkv = t @ w_qkv, scatter to (B,H,N,4) ----------------
__global__ __launch_bounds__(192) void qkv_kernel(const float* __restrict__ t,
                                                  const float* __restrict__ w_qkv,
                                                  float* __restrict__ q,
                                                  float* __restrict__ k,
                                                  float* __restrict__ v) {
    __shared__ float trow[16 * 64];                     // 16 token rows
    int tid = threadIdx.x;                              // 0..191 (j = output column)
    int row0 = blockIdx.x * 16;
    for (int i = tid; i < 1024; i += 192) trow[i] = t[row0 * 64 + i];
    float wcol[64];                                     // my w_qkv column, in registers
    #pragma unroll
    for (int c = 0; c < 64; c++) wcol[c] = w_qkv[c * 192 + tid];
    __syncthreads();
    int s = tid >> 6, h = (tid >> 2) & 15, d = tid & 3;
    float* dst = (s == 0) ? q : (s == 1) ? k : v;
    for (int r = 0; r < 16; r++) {
        const float4* tr = (const float4*)&trow[r * 64];
        float acc = 0.f;
        #pragma unroll
        for (int c4 = 0; c4 < 16; c4++) {
            float4 tv = tr[c4];                         // LDS broadcast (all lanes same addr)
            acc += tv.x * wcol[c4 * 4] + tv.y * wcol[c4 * 4 + 1]
                 + tv.z * wcol[c4 * 4 + 2] + tv.w * wcol[c4 * 4 + 3];
        }
        int ng = row0 + r, b = ng >> 10, n = ng & 1023;
        dst[((b * 16 + h) * 1024 + n) * 4 + d] = acc;
    }
}

// ---------------- Kernel C: flash-style attention, R=4 rows/thread, 4-way key split --
// grid = 128 (b,h) * 4 key-chunks. Each block: all 1024 q rows, 256 keys in LDS (8 KB).
// Each thread owns 4 rows -> each K/V ds_read_b128 is amortized over 4 rows (the R1
// kernel was LDS-return-bus-bound at 2 reads/key/thread). Partials combined with
// fp32 atomicAdd (softmax sans max-subtract is a plain sum; scores bounded << 88).
__global__ __launch_bounds__(256) void attn_kernel(const float* __restrict__ q,
                                                   const float* __restrict__ k,
                                                   const float* __restrict__ v,
                                                   float* __restrict__ o,
                                                   float* __restrict__ l) {
    __shared__ float4 kvs[512];                         // [0,256)=K chunk, [256,512)=V chunk
    int bh = blockIdx.x >> 2, chunk = blockIdx.x & 3;
    int tid = threadIdx.x;
    const float4* kp = (const float4*)(k + bh * 4096) + chunk * 256;
    const float4* vp = (const float4*)(v + bh * 4096) + chunk * 256;
    kvs[tid] = kp[tid];
    kvs[256 + tid] = vp[tid];
    __syncthreads();
    const float C1 = 0.5f * 1.44269504088896f;          // scale * log2(e), folded into q
    const float4* qp = (const float4*)(q + bh * 4096);
    float4 q0 = qp[tid], q1 = qp[256 + tid], q2 = qp[512 + tid], q3 = qp[768 + tid];
    q0.x *= C1; q0.y *= C1; q0.z *= C1; q0.w *= C1;
    q1.x *= C1; q1.y *= C1; q1.z *= C1; q1.w *= C1;
    q2.x *= C1; q2.y *= C1; q2.z *= C1; q2.w *= C1;
    q3.x *= C1; q3.y *= C1; q3.z *= C1; q3.w *= C1;
    float l0 = 0.f, l1 = 0.f, l2 = 0.f, l3 = 0.f;
    float4 a0 = {0,0,0,0}, a1 = {0,0,0,0}, a2 = {0,0,0,0}, a3 = {0,0,0,0};
    #pragma unroll 4
    for (int key = 0; key < 256; key++) {
        float4 kk = kvs[key];                           // broadcast: conflict-free
        float4 vv = kvs[256 + key];
        float s0 = q0.x * kk.x + q0.y * kk.y + q0.z * kk.z + q0.w * kk.w;
        float s1 = q1.x * kk.x + q1.y * kk.y + q1.z * kk.z + q1.w * kk.w;
        float s2 = q2.x * kk.x + q2.y * kk.y + q2.z * kk.z + q2.w * kk.w;
        float s3 = q3.x * kk.x + q3.y * kk.y + q3.z * kk.z + q3.w * kk.w;
        float p0 = __builtin_exp2f(s0);
        float p1 = __builtin_exp2f(s1);
        float p2 = __builtin_exp2f(s2);
        float p3 = __builtin_exp2f(s3);
        l0 += p0; l1 += p1; l2 += p2; l3 += p3;
        a0.x += p0 * vv.x; a0.y += p0 * vv.y; a0.z += p0 * vv.z; a0.w += p0 * vv.w;
        a1.x += p1 * vv.x; a1.y += p1 * vv.y; a1.z += p1 * vv.z; a1.w += p1 * vv.w;
        a2.x += p2 * vv.x; a2.y += p2 * vv.y; a2.z += p2 * vv.z; a2.w += p2 * vv.w;
        a3.x += p3 * vv.x; a3.y += p3 * vv.y; a3.z += p3 * vv.z; a3.w += p3 * vv.w;
    }
    int b = bh >> 4, h = bh & 15;
    float* ob = o + (b * 1024) * 64 + h * 4;
    float* lb = l + (b * 1024) * 16 + h;
    #pragma unroll
    for (int r = 0; r < 4; r++) {
        int row = r * 256 + tid;
        float4 ar = (r == 0) ? a0 : (r == 1) ? a1 : (r == 2) ? a2 : a3;
        float lr = (r == 0) ? l0 : (r == 1) ? l1 : (r == 2) ? l2 : l3;
        float* op = ob + row * 64;
        atomicAdd(op + 0, ar.x);
        atomicAdd(op + 1, ar.y);
        atomicAdd(op + 2, ar.z);
        atomicAdd(op + 3, ar.w);
        atomicAdd(lb + row * 16, lr);
    }
}

// ---------------- Kernel D: normalize + o @ w_proj + BN + max-unpool scatter --------
__global__ __launch_bounds__(256) void proj_kernel(const float* __restrict__ o,
                                                   const float* __restrict__ l,
                                                   const float* __restrict__ w_proj,
                                                   const float* __restrict__ gamma,
                                                   const float* __restrict__ beta,
                                                   const float* __restrict__ mean,
                                                   const float* __restrict__ var,
                                                   const int* __restrict__ idx,
                                                   float* __restrict__ out) {
    __shared__ float ws[64 * 64];                       // w_proj
    int b = blockIdx.x >> 5, hp = blockIdx.x & 31;
    int tid = threadIdx.x;
    for (int i = tid; i < 4096; i += 256) ws[i] = w_proj[i];
    int wp = tid & 31, cg = tid >> 5;                   // 8 c-groups x 32 wp
    int row = b * 1024 + hp * 32 + wp;
    float oreg[64];                                     // my o row in registers
    const float4* orow = (const float4*)(o + row * 64);
    const float4* lrow = (const float4*)(l + row * 16);
    #pragma unroll
    for (int h4 = 0; h4 < 4; h4++) {
        float4 lv = lrow[h4];
        float4 i0 = orow[h4 * 4 + 0], i1 = orow[h4 * 4 + 1];
        float4 i2 = orow[h4 * 4 + 2], i3 = orow[h4 * 4 + 3];
        float r0 = 1.f / lv.x, r1 = 1.f / lv.y, r2 = 1.f / lv.z, r3 = 1.f / lv.w;
        oreg[h4*16+ 0] = i0.x*r0; oreg[h4*16+ 1] = i0.y*r0; oreg[h4*16+ 2] = i0.z*r0; oreg[h4*16+ 3] = i0.w*r0;
        oreg[h4*16+ 4] = i1.x*r1; oreg[h4*16+ 5] = i1.y*r1; oreg[h4*16+ 6] = i1.z*r1; oreg[h4*16+ 7] = i1.w*r1;
        oreg[h4*16+ 8] = i2.x*r2; oreg[h4*16+ 9] = i2.y*r2; oreg[h4*16+10] = i2.z*r2; oreg[h4*16+11] = i2.w*r2;
        oreg[h4*16+12] = i3.x*r3; oreg[h4*16+13] = i3.y*r3; oreg[h4*16+14] = i3.z*r3; oreg[h4*16+15] = i3.w*r3;
    }
    __syncthreads();
    #pragma unroll
    for (int cc = 0; cc < 8; cc++) {
        int c = cg + 8 * cc;                            // 8 distinct banks -> conflict-free
        float acc = 0.f;
        #pragma unroll
        for (int a = 0; a < 64; a++) acc += oreg[a] * ws[a * 64 + c];
        float inv = gamma[c] * rsqrtf(var[c] + 1e-5f);
        float val = acc * inv + (beta[c] - mean[c] * inv);
        int id = idx[((b * 64 + c) * 32 + hp) * 32 + wp];
        int base = ((b * 64 + c) * 64 + 2 * hp) * 64 + 2 * wp;
        float2 r0 = { id == 0 ? val : 0.f, id == 1 ? val : 0.f };
        float2 r1 = { id == 2 ? val : 0.f, id == 3 ? val : 0.f };
        *(float2*)&out[base] = r0;                      // row 2hp,   cols 2wp..2wp+1
        *(float2*)&out[base + 64] = r1;                 // row 2hp+1
    }
}

extern "C" void kernel_launch(void* const* d_in, const int* in_sizes, int n_in,
                              void* d_out, int out_size, void* d_ws, size_t ws_size,
                              hipStream_t stream) {
    const float* x      = (const float*)d_in[0];
    const float* w_qkv  = (const float*)d_in[1];
    const float* w_proj = (const float*)d_in[2];
    const float* gamma  = (const float*)d_in[3];
    const float* beta   = (const float*)d_in[4];
    const float* bn_mean= (const float*)d_in[5];
    const float* bn_var = (const float*)d_in[6];
    float* out = (float*)d_out;

    const int SEG = 524288;                             // 8*1024*64
    float* ws = (float*)d_ws;
    float* t   = ws;
    int*   idx = (int*)(ws + SEG);
    float* q   = ws + 2 * SEG;
    float* k   = ws + 3 * SEG;
    float* v   = ws + 4 * SEG;
    float* o   = ws + 5 * SEG;
    float* l   = ws + 6 * SEG;                          // 131072 floats

    pool_kernel<<<2048, 256, 0, stream>>>(x, t, idx, o, l);
    qkv_kernel<<<512, 192, 0, stream>>>(t, w_qkv, q, k, v);
    attn_kernel<<<512, 256, 0, stream>>>(q, k, v, o, l);
    proj_kernel<<<256, 256, 0, stream>>>(o, l, w_proj, gamma, beta, bn_mean, bn_var, idx, out);
}

// Round 3
// 163.034 us; speedup vs baseline: 1.6276x; 1.6276x over previous
//
#include <hip/hip_runtime.h>
#include <hip/hip_bf16.h>

// Problem: B=8, C=DIM=64, H=W=64 -> pooled 32x32 (N=1024 tokens), 16 heads x d=4.
// ws layout (floats):
//   t[524288] | idx[524288 ints] | q[524288] | k[524288] | v[524288]
//   | o_part[512 * 5120]   (per (bh,chunk) slab: [0,4096)=numerator float4 per n,
//                           [4096,5120)=denominator per n)
// q/k/v layout: (B, H=16, N=1024, D=4) contiguous -> per (b,h) a 4096-float slab.

// ---------------- Kernel A: 2x2 maxpool + argmax ----------------
__global__ __launch_bounds__(256) void pool_kernel(const float* __restrict__ x,
                                                   float* __restrict__ t,
                                                   int* __restrict__ idx) {
    int g = blockIdx.x * 256 + threadIdx.x;            // covers 8*64*32*32 = 524288
    int wp = g & 31, hp = (g >> 5) & 31, c = (g >> 10) & 63, b = g >> 16;
    const float* px = x + (((b * 64 + c) * 64 + 2 * hp) * 64 + 2 * wp);
    float2 r0 = *(const float2*)px;
    float2 r1 = *(const float2*)(px + 64);
    float best = r0.x; int bi = 0;                      // first-max semantics (strict >)
    if (r0.y > best) { best = r0.y; bi = 1; }
    if (r1.x > best) { best = r1.x; bi = 2; }
    if (r1.y > best) { best = r1.y; bi = 3; }
    int n = hp * 32 + wp;
    t[(b * 1024 + n) * 64 + c] = best;
    idx[g] = bi;                                        // layout (b,c,hp,wp)
}

// ---------------- Kernel B: qkv = t @ w_qkv, scatter to (B,H,N,4) ----------------
__global__ __launch_bounds__(192) void qkv_kernel(const float* __restrict__ t,
                                                  const float* __restrict__ w_qkv,
                                                  float* __restrict__ q,
                                                  float* __restrict__ k,
                                                  float* __restrict__ v) {
    __shared__ float trow[16 * 64];                     // 16 token rows
    int tid = threadIdx.x;                              // 0..191 (j = output column)
    int row0 = blockIdx.x * 16;
    for (int i = tid; i < 1024; i += 192) trow[i] = t[row0 * 64 + i];
    float wcol[64];                                     // my w_qkv column, in registers
    #pragma unroll
    for (int c = 0; c < 64; c++) wcol[c] = w_qkv[c * 192 + tid];
    __syncthreads();
    int s = tid >> 6, h = (tid >> 2) & 15, d = tid & 3;
    float* dst = (s == 0) ? q : (s == 1) ? k : v;
    for (int r = 0; r < 16; r++) {
        const float4* tr = (const float4*)&trow[r * 64];
        float acc = 0.f;
        #pragma unroll
        for (int c4 = 0; c4 < 16; c4++) {
            float4 tv = tr[c4];                         // LDS broadcast (all lanes same addr)
            acc += tv.x * wcol[c4 * 4] + tv.y * wcol[c4 * 4 + 1]
                 + tv.z * wcol[c4 * 4 + 2] + tv.w * wcol[c4 * 4 + 3];
        }
        int ng = row0 + r, b = ng >> 10, n = ng & 1023;
        dst[((b * 16 + h) * 1024 + n) * 4 + d] = acc;
    }
}

// ---------------- Kernel C: flash-style attention, R=4 rows/thread, 4-way key split --
// grid = 128 (b,h) * 4 key-chunks. Each block: all 1024 q rows, 256 keys in LDS (8 KB).
// Each K/V ds_read_b128 is amortized over 4 rows (R1 was LDS-return-bus-bound).
// Partials go to a private per-block slab with plain coalesced stores (R2's global
// atomics caused 80 MB of HBM write-through; this is 10.5 MB of plain stores).
// Scores bounded (|s|<~20 << 88) so exp without max-subtract is exact-in-softmax.
__global__ __launch_bounds__(256) void attn_kernel(const float* __restrict__ q,
                                                   const float* __restrict__ k,
                                                   const float* __restrict__ v,
                                                   float* __restrict__ o_part) {
    __shared__ float4 kvs[512];                         // [0,256)=K chunk, [256,512)=V chunk
    int bh = blockIdx.x >> 2, chunk = blockIdx.x & 3;
    int tid = threadIdx.x;
    const float4* kp = (const float4*)(k + bh * 4096) + chunk * 256;
    const float4* vp = (const float4*)(v + bh * 4096) + chunk * 256;
    kvs[tid] = kp[tid];
    kvs[256 + tid] = vp[tid];
    __syncthreads();
    const float C1 = 0.5f * 1.44269504088896f;          // scale * log2(e), folded into q
    const float4* qp = (const float4*)(q + bh * 4096);
    float4 q0 = qp[tid], q1 = qp[256 + tid], q2 = qp[512 + tid], q3 = qp[768 + tid];
    q0.x *= C1; q0.y *= C1; q0.z *= C1; q0.w *= C1;
    q1.x *= C1; q1.y *= C1; q1.z *= C1; q1.w *= C1;
    q2.x *= C1; q2.y *= C1; q2.z *= C1; q2.w *= C1;
    q3.x *= C1; q3.y *= C1; q3.z *= C1; q3.w *= C1;
    float l0 = 0.f, l1 = 0.f, l2 = 0.f, l3 = 0.f;
    float4 a0 = {0,0,0,0}, a1 = {0,0,0,0}, a2 = {0,0,0,0}, a3 = {0,0,0,0};
    #pragma unroll 4
    for (int key = 0; key < 256; key++) {
        float4 kk = kvs[key];                           // broadcast: conflict-free
        float4 vv = kvs[256 + key];
        float s0 = q0.x * kk.x + q0.y * kk.y + q0.z * kk.z + q0.w * kk.w;
        float s1 = q1.x * kk.x + q1.y * kk.y + q1.z * kk.z + q1.w * kk.w;
        float s2 = q2.x * kk.x + q2.y * kk.y + q2.z * kk.z + q2.w * kk.w;
        float s3 = q3.x * kk.x + q3.y * kk.y + q3.z * kk.z + q3.w * kk.w;
        float p0 = __builtin_exp2f(s0);
        float p1 = __builtin_exp2f(s1);
        float p2 = __builtin_exp2f(s2);
        float p3 = __builtin_exp2f(s3);
        l0 += p0; l1 += p1; l2 += p2; l3 += p3;
        a0.x += p0 * vv.x; a0.y += p0 * vv.y; a0.z += p0 * vv.z; a0.w += p0 * vv.w;
        a1.x += p1 * vv.x; a1.y += p1 * vv.y; a1.z += p1 * vv.z; a1.w += p1 * vv.w;
        a2.x += p2 * vv.x; a2.y += p2 * vv.y; a2.z += p2 * vv.z; a2.w += p2 * vv.w;
        a3.x += p3 * vv.x; a3.y += p3 * vv.y; a3.z += p3 * vv.z; a3.w += p3 * vv.w;
    }
    float* slab = o_part + blockIdx.x * 5120;           // private slab, coalesced stores
    #pragma unroll
    for (int r = 0; r < 4; r++) {
        int n = r * 256 + tid;
        float4 ar = (r == 0) ? a0 : (r == 1) ? a1 : (r == 2) ? a2 : a3;
        float lr = (r == 0) ? l0 : (r == 1) ? l1 : (r == 2) ? l2 : l3;
        *(float4*)&slab[n * 4] = ar;
        slab[4096 + n] = lr;
    }
}

// ---------------- Kernel D: combine partials + o @ w_proj + BN + max-unpool ---------
__global__ __launch_bounds__(256) void proj_kernel(const float* __restrict__ o_part,
                                                   const float* __restrict__ w_proj,
                                                   const float* __restrict__ gamma,
                                                   const float* __restrict__ beta,
                                                   const float* __restrict__ mean,
                                                   const float* __restrict__ var,
                                                   const int* __restrict__ idx,
                                                   float* __restrict__ out) {
    __shared__ float ws[64 * 64];                       // w_proj
    int b = blockIdx.x >> 5, hp = blockIdx.x & 31;
    int tid = threadIdx.x;
    for (int i = tid; i < 4096; i += 256) ws[i] = w_proj[i];
    int wp = tid & 31, cg = tid >> 5;                   // 8 c-groups x 32 wp
    int n = hp * 32 + wp;
    float oreg[64];                                     // normalized o row in registers
    #pragma unroll
    for (int h = 0; h < 16; h++) {
        const float* base = o_part + ((b * 16 + h) * 4) * 5120;
        float4 osum = {0, 0, 0, 0}; float lsum = 0.f;
        #pragma unroll
        for (int c = 0; c < 4; c++) {
            const float* sl = base + c * 5120;
            float4 t4 = *(const float4*)&sl[n * 4];     // coalesced across wp lanes
            osum.x += t4.x; osum.y += t4.y; osum.z += t4.z; osum.w += t4.w;
            lsum += sl[4096 + n];
        }
        float r = 1.f / lsum;
        oreg[h * 4 + 0] = osum.x * r; oreg[h * 4 + 1] = osum.y * r;
        oreg[h * 4 + 2] = osum.z * r; oreg[h * 4 + 3] = osum.w * r;
    }
    __syncthreads();
    #pragma unroll
    for (int cc = 0; cc < 8; cc++) {
        int c = cg + 8 * cc;                            // 8 distinct banks -> conflict-free
        float acc = 0.f;
        #pragma unroll
        for (int a = 0; a < 64; a++) acc += oreg[a] * ws[a * 64 + c];
        float inv = gamma[c] * rsqrtf(var[c] + 1e-5f);
        float val = acc * inv + (beta[c] - mean[c] * inv);
        int id = idx[((b * 64 + c) * 32 + hp) * 32 + wp];
        int base = ((b * 64 + c) * 64 + 2 * hp) * 64 + 2 * wp;
        float2 r0 = { id == 0 ? val : 0.f, id == 1 ? val : 0.f };
        float2 r1 = { id == 2 ? val : 0.f, id == 3 ? val : 0.f };
        *(float2*)&out[base] = r0;                      // row 2hp,   cols 2wp..2wp+1
        *(float2*)&out[base + 64] = r1;                 // row 2hp+1
    }
}

extern "C" void kernel_launch(void* const* d_in, const int* in_sizes, int n_in,
                              void* d_out, int out_size, void* d_ws, size_t ws_size,
                              hipStream_t stream) {
    const float* x      = (const float*)d_in[0];
    const float* w_qkv  = (const float*)d_in[1];
    const float* w_proj = (const float*)d_in[2];
    const float* gamma  = (const float*)d_in[3];
    const float* beta   = (const float*)d_in[4];
    const float* bn_mean= (const float*)d_in[5];
    const float* bn_var = (const float*)d_in[6];
    float* out = (float*)d_out;

    const int SEG = 524288;                             // 8*1024*64
    float* ws = (float*)d_ws;
    float* t      = ws;
    int*   idx    = (int*)(ws + SEG);
    float* q      = ws + 2 * SEG;
    float* k      = ws + 3 * SEG;
    float* v      = ws + 4 * SEG;
    float* o_part = ws + 5 * SEG;                       // 512 * 5120 floats = 10.5 MB

    pool_kernel<<<2048, 256, 0, stream>>>(x, t, idx);
    qkv_kernel<<<512, 192, 0, stream>>>(t, w_qkv, q, k, v);
    attn_kernel<<<512, 256, 0, stream>>>(q, k, v, o_part);
    proj_kernel<<<256, 256, 0, stream>>>(o_part, w_proj, gamma, beta, bn_mean, bn_var, idx, out);
}

// Round 4
// 152.303 us; speedup vs baseline: 1.7423x; 1.0705x over previous
//
#include <hip/hip_runtime.h>
#include <hip/hip_bf16.h>

// Problem: B=8, C=DIM=64, H=W=64 -> pooled 32x32 (N=1024 tokens), 16 heads x d=4.
// ws layout (floats):
//   t[524288] | idx[524288 ints] | q[524288] | k[524288] | v[524288]
//   | o_part[512 * 5120]   (per (bh,chunk) slab: [0,4096)=numerator float4 per n,
//                           [4096,5120)=denominator per n)
// q/k/v layout: (B, H=16, N=1024, D=4) contiguous -> per (b,h) a 4096-float slab.

// ---------------- Kernel A: 2x2 maxpool + argmax ----------------
__global__ __launch_bounds__(256) void pool_kernel(const float* __restrict__ x,
                                                   float* __restrict__ t,
                                                   int* __restrict__ idx) {
    int g = blockIdx.x * 256 + threadIdx.x;            // covers 8*64*32*32 = 524288
    int wp = g & 31, hp = (g >> 5) & 31, c = (g >> 10) & 63, b = g >> 16;
    const float* px = x + (((b * 64 + c) * 64 + 2 * hp) * 64 + 2 * wp);
    float2 r0 = *(const float2*)px;
    float2 r1 = *(const float2*)(px + 64);
    float best = r0.x; int bi = 0;                      // first-max semantics (strict >)
    if (r0.y > best) { best = r0.y; bi = 1; }
    if (r1.x > best) { best = r1.x; bi = 2; }
    if (r1.y > best) { best = r1.y; bi = 3; }
    int n = hp * 32 + wp;
    t[(b * 1024 + n) * 64 + c] = best;
    idx[g] = bi;                                        // layout (b,c,hp,wp)
}

// ---------------- Kernel B: qkv = t @ w_qkv, scatter to (B,H,N,4) ----------------
__global__ __launch_bounds__(192) void qkv_kernel(const float* __restrict__ t,
                                                  const float* __restrict__ w_qkv,
                                                  float* __restrict__ q,
                                                  float* __restrict__ k,
                                                  float* __restrict__ v) {
    __shared__ float trow[16 * 64];                     // 16 token rows
    int tid = threadIdx.x;                              // 0..191 (j = output column)
    int row0 = blockIdx.x * 16;
    for (int i = tid; i < 1024; i += 192) trow[i] = t[row0 * 64 + i];
    float wcol[64];                                     // my w_qkv column, in registers
    #pragma unroll
    for (int c = 0; c < 64; c++) wcol[c] = w_qkv[c * 192 + tid];
    __syncthreads();
    int s = tid >> 6, h = (tid >> 2) & 15, d = tid & 3;
    float* dst = (s == 0) ? q : (s == 1) ? k : v;
    for (int r = 0; r < 16; r++) {
        const float4* tr = (const float4*)&trow[r * 64];
        float acc = 0.f;
        #pragma unroll
        for (int c4 = 0; c4 < 16; c4++) {
            float4 tv = tr[c4];                         // LDS broadcast (all lanes same addr)
            acc += tv.x * wcol[c4 * 4] + tv.y * wcol[c4 * 4 + 1]
                 + tv.z * wcol[c4 * 4 + 2] + tv.w * wcol[c4 * 4 + 3];
        }
        int ng = row0 + r, b = ng >> 10, n = ng & 1023;
        dst[((b * 16 + h) * 1024 + n) * 4 + d] = acc;
    }
}

// ---------------- Kernel C: flash attention, R=8 rows/thread, in-block key split ----
// grid = 128 (b,h) * 4 key-chunks of 256 keys. 256 threads = two 128-thread halves;
// each half processes 128 keys for ALL 1024 rows (8 rows/thread), halving the
// ds_read_b128 count per (row,key) pair vs R3. Halves combine via LDS at the end.
// exp via raw v_exp_f32 (__builtin_amdgcn_exp2f): scores bounded |s|<~14 << 126 so
// the library's denormal-range guard is dead code for us; softmax shift-invariance
// makes max-subtraction unnecessary.
__global__ __launch_bounds__(256) void attn_kernel(const float* __restrict__ q,
                                                   const float* __restrict__ k,
                                                   const float* __restrict__ v,
                                                   float* __restrict__ o_part) {
    __shared__ float4 kvs[512];                         // [0,256)=K chunk, [256,512)=V chunk
    __shared__ float4 part_a[8 * 128];                  // half-1 numerator partials
    __shared__ float  part_l[8 * 128];                  // half-1 denominator partials
    int bh = blockIdx.x >> 2, chunk = blockIdx.x & 3;
    int tid = threadIdx.x;
    const float4* kp = (const float4*)(k + bh * 4096) + chunk * 256;
    const float4* vp = (const float4*)(v + bh * 4096) + chunk * 256;
    kvs[tid] = kp[tid];
    kvs[256 + tid] = vp[tid];
    int half = tid >> 7;                                // wave-uniform (waves 0,1 vs 2,3)
    int lane = tid & 127;
    const float C1 = 0.5f * 1.44269504088896f;          // scale * log2(e), folded into q
    const float4* qp = (const float4*)(q + bh * 4096);
    float4 qr[8];
    #pragma unroll
    for (int r = 0; r < 8; r++) {
        float4 t4 = qp[r * 128 + lane];                 // coalesced; 2x redundant (L1/L2)
        qr[r].x = t4.x * C1; qr[r].y = t4.y * C1;
        qr[r].z = t4.z * C1; qr[r].w = t4.w * C1;
    }
    __syncthreads();
    float lr[8];
    float4 ar[8];
    #pragma unroll
    for (int r = 0; r < 8; r++) { lr[r] = 0.f; ar[r] = make_float4(0.f, 0.f, 0.f, 0.f); }
    int k0 = half * 128;
    #pragma unroll 2
    for (int key = k0; key < k0 + 128; key++) {
        float4 kk = kvs[key];                           // broadcast: conflict-free
        float4 vv = kvs[256 + key];
        #pragma unroll
        for (int r = 0; r < 8; r++) {
            float s = qr[r].x * kk.x + qr[r].y * kk.y + qr[r].z * kk.z + qr[r].w * kk.w;
            float p = __builtin_amdgcn_exp2f(s);        // bare v_exp_f32
            lr[r] += p;
            ar[r].x += p * vv.x; ar[r].y += p * vv.y;
            ar[r].z += p * vv.z; ar[r].w += p * vv.w;
        }
    }
    if (half == 1) {                                    // wave-uniform branch
        #pragma unroll
        for (int r = 0; r < 8; r++) {
            part_a[r * 128 + lane] = ar[r];             // float4 stride: 2-way alias, free
            part_l[r * 128 + lane] = lr[r];
        }
    }
    __syncthreads();
    if (half == 0) {
        float* slab = o_part + blockIdx.x * 5120;       // private slab, coalesced stores
        #pragma unroll
        for (int r = 0; r < 8; r++) {
            float4 pa = part_a[r * 128 + lane];
            float  pl = part_l[r * 128 + lane];
            int n = r * 128 + lane;
            float4 sum = { ar[r].x + pa.x, ar[r].y + pa.y,
                           ar[r].z + pa.z, ar[r].w + pa.w };
            *(float4*)&slab[n * 4] = sum;
            slab[4096 + n] = lr[r] + pl;
        }
    }
}

// ---------------- Kernel D: combine partials + o @ w_proj + BN + max-unpool ---------
__global__ __launch_bounds__(256) void proj_kernel(const float* __restrict__ o_part,
                                                   const float* __restrict__ w_proj,
                                                   const float* __restrict__ gamma,
                                                   const float* __restrict__ beta,
                                                   const float* __restrict__ mean,
                                                   const float* __restrict__ var,
                                                   const int* __restrict__ idx,
                                                   float* __restrict__ out) {
    __shared__ float ws[64 * 64];                       // w_proj
    int b = blockIdx.x >> 5, hp = blockIdx.x & 31;
    int tid = threadIdx.x;
    for (int i = tid; i < 4096; i += 256) ws[i] = w_proj[i];
    int wp = tid & 31, cg = tid >> 5;                   // 8 c-groups x 32 wp
    int n = hp * 32 + wp;
    float oreg[64];                                     // normalized o row in registers
    #pragma unroll
    for (int h = 0; h < 16; h++) {
        const float* base = o_part + ((b * 16 + h) * 4) * 5120;
        float4 osum = {0, 0, 0, 0}; float lsum = 0.f;
        #pragma unroll
        for (int c = 0; c < 4; c++) {
            const float* sl = base + c * 5120;
            float4 t4 = *(const float4*)&sl[n * 4];     // coalesced across wp lanes
            osum.x += t4.x; osum.y += t4.y; osum.z += t4.z; osum.w += t4.w;
            lsum += sl[4096 + n];
        }
        float r = 1.f / lsum;
        oreg[h * 4 + 0] = osum.x * r; oreg[h * 4 + 1] = osum.y * r;
        oreg[h * 4 + 2] = osum.z * r; oreg[h * 4 + 3] = osum.w * r;
    }
    __syncthreads();
    #pragma unroll
    for (int cc = 0; cc < 8; cc++) {
        int c = cg + 8 * cc;                            // 8 distinct banks -> conflict-free
        float acc = 0.f;
        #pragma unroll
        for (int a = 0; a < 64; a++) acc += oreg[a] * ws[a * 64 + c];
        float inv = gamma[c] * rsqrtf(var[c] + 1e-5f);
        float val = acc * inv + (beta[c] - mean[c] * inv);
        int id = idx[((b * 64 + c) * 32 + hp) * 32 + wp];
        int base = ((b * 64 + c) * 64 + 2 * hp) * 64 + 2 * wp;
        float2 r0 = { id == 0 ? val : 0.f, id == 1 ? val : 0.f };
        float2 r1 = { id == 2 ? val : 0.f, id == 3 ? val : 0.f };
        *(float2*)&out[base] = r0;                      // row 2hp,   cols 2wp..2wp+1
        *(float2*)&out[base + 64] = r1;                 // row 2hp+1
    }
}

extern "C" void kernel_launch(void* const* d_in, const int* in_sizes, int n_in,
                              void* d_out, int out_size, void* d_ws, size_t ws_size,
                              hipStream_t stream) {
    const float* x      = (const float*)d_in[0];
    const float* w_qkv  = (const float*)d_in[1];
    const float* w_proj = (const float*)d_in[2];
    const float* gamma  = (const float*)d_in[3];
    const float* beta   = (const float*)d_in[4];
    const float* bn_mean= (const float*)d_in[5];
    const float* bn_var = (const float*)d_in[6];
    float* out = (float*)d_out;

    const int SEG = 524288;                             // 8*1024*64
    float* ws = (float*)d_ws;
    float* t      = ws;
    int*   idx    = (int*)(ws + SEG);
    float* q      = ws + 2 * SEG;
    float* k      = ws + 3 * SEG;
    float* v      = ws + 4 * SEG;
    float* o_part = ws + 5 * SEG;                       // 512 * 5120 floats = 10.5 MB

    pool_kernel<<<2048, 256, 0, stream>>>(x, t, idx);
    qkv_kernel<<<512, 192, 0, stream>>>(t, w_qkv, q, k, v);
    attn_kernel<<<512, 256, 0, stream>>>(q, k, v, o_part);
    proj_kernel<<<256, 256, 0, stream>>>(o_part, w_proj, gamma, beta, bn_mean, bn_var, idx, out);
}

// Round 5
// 149.238 us; speedup vs baseline: 1.7781x; 1.0205x over previous
//
#include <hip/hip_runtime.h>
#include <hip/hip_bf16.h>

// Problem: B=8, C=DIM=64, H=W=64 -> pooled 32x32 (N=1024 tokens), 16 heads x d=4.
// ws layout (floats):
//   t[524288] | idx[524288 ints] | q[524288] | k[524288] | v[524288]
//   | o_part[512 * 5120]   (per (bh,chunk) slab: [0,4096)=numerator float4 per n,
//                           [4096,5120)=denominator per n)
// q/k/v layout: (B, H=16, N=1024, D=4) contiguous -> per (b,h) a 4096-float slab.

// ---------------- Kernel A: 2x2 maxpool + argmax ----------------
__global__ __launch_bounds__(256) void pool_kernel(const float* __restrict__ x,
                                                   float* __restrict__ t,
                                                   int* __restrict__ idx) {
    int g = blockIdx.x * 256 + threadIdx.x;            // covers 8*64*32*32 = 524288
    int wp = g & 31, hp = (g >> 5) & 31, c = (g >> 10) & 63, b = g >> 16;
    const float* px = x + (((b * 64 + c) * 64 + 2 * hp) * 64 + 2 * wp);
    float2 r0 = *(const float2*)px;
    float2 r1 = *(const float2*)(px + 64);
    float best = r0.x; int bi = 0;                      // first-max semantics (strict >)
    if (r0.y > best) { best = r0.y; bi = 1; }
    if (r1.x > best) { best = r1.x; bi = 2; }
    if (r1.y > best) { best = r1.y; bi = 3; }
    int n = hp * 32 + wp;
    t[(b * 1024 + n) * 64 + c] = best;
    idx[g] = bi;                                        // layout (b,c,hp,wp)
}

// ---------------- Kernel B: qkv = t @ w_qkv, scatter to (B,H,N,4) ----------------
__global__ __launch_bounds__(192) void qkv_kernel(const float* __restrict__ t,
                                                  const float* __restrict__ w_qkv,
                                                  float* __restrict__ q,
                                                  float* __restrict__ k,
                                                  float* __restrict__ v) {
    __shared__ float trow[16 * 64];                     // 16 token rows
    int tid = threadIdx.x;                              // 0..191 (j = output column)
    int row0 = blockIdx.x * 16;
    for (int i = tid; i < 1024; i += 192) trow[i] = t[row0 * 64 + i];
    float wcol[64];                                     // my w_qkv column, in registers
    #pragma unroll
    for (int c = 0; c < 64; c++) wcol[c] = w_qkv[c * 192 + tid];
    __syncthreads();
    int s = tid >> 6, h = (tid >> 2) & 15, d = tid & 3;
    float* dst = (s == 0) ? q : (s == 1) ? k : v;
    for (int r = 0; r < 16; r++) {
        const float4* tr = (const float4*)&trow[r * 64];
        float acc = 0.f;
        #pragma unroll
        for (int c4 = 0; c4 < 16; c4++) {
            float4 tv = tr[c4];                         // LDS broadcast (all lanes same addr)
            acc += tv.x * wcol[c4 * 4] + tv.y * wcol[c4 * 4 + 1]
                 + tv.z * wcol[c4 * 4 + 2] + tv.w * wcol[c4 * 4 + 3];
        }
        int ng = row0 + r, b = ng >> 10, n = ng & 1023;
        dst[((b * 16 + h) * 1024 + n) * 4 + d] = acc;
    }
}

// ---------------- Kernel C: flash attention, 4-way per-wave key split + row halves --
// grid = 128 (b,h) * 4 key-chunks * 2 row-halves = 1024 blocks (4 blocks/CU,
// 4 waves/SIMD -- R4 had only 2 waves/SIMD and VALUBusy stalled at 63%).
// Block: 256 keys in LDS; wave w handles keys [64w,64w+64) for all 512 rows of its
// row-half (R=8 rows/thread, so total ds_read count is unchanged vs R4 = ~10 us).
// Wave partials combine via LDS; the two row-half blocks write disjoint rows of the
// SAME o_part slab (no extra workspace; proj_kernel unchanged).
// exp via raw v_exp_f32: |s| < ~14 << 126, softmax shift-invariance.
__global__ __launch_bounds__(256) void attn_kernel(const float* __restrict__ q,
                                                   const float* __restrict__ k,
                                                   const float* __restrict__ v,
                                                   float* __restrict__ o_part) {
    __shared__ float4 kvs[512];                         // [0,256)=K chunk, [256,512)=V chunk
    __shared__ float4 pa[3 * 512];                      // waves 1..3 numerator partials
    __shared__ float  pl[3 * 512];                      // waves 1..3 denominator partials
    int bh = blockIdx.x >> 3;
    int chunk = (blockIdx.x >> 1) & 3;                  // key chunk (256 keys)
    int rh = blockIdx.x & 1;                            // row half (512 rows)
    int tid = threadIdx.x;
    const float4* kp = (const float4*)(k + bh * 4096) + chunk * 256;
    const float4* vp = (const float4*)(v + bh * 4096) + chunk * 256;
    kvs[tid] = kp[tid];
    kvs[256 + tid] = vp[tid];
    int w = tid >> 6;                                   // wave id 0..3 (wave-uniform)
    int lane = tid & 63;
    const float C1 = 0.5f * 1.44269504088896f;          // scale * log2(e), folded into q
    const float4* qp = (const float4*)(q + bh * 4096) + rh * 512;
    float4 qr[8];
    #pragma unroll
    for (int r = 0; r < 8; r++) {
        float4 t4 = qp[r * 64 + lane];                  // coalesced 1 KB/wave
        qr[r].x = t4.x * C1; qr[r].y = t4.y * C1;
        qr[r].z = t4.z * C1; qr[r].w = t4.w * C1;
    }
    __syncthreads();
    float lr[8];
    float4 ar[8];
    #pragma unroll
    for (int r = 0; r < 8; r++) { lr[r] = 0.f; ar[r] = make_float4(0.f, 0.f, 0.f, 0.f); }
    int k0 = w * 64;
    #pragma unroll 2
    for (int key = k0; key < k0 + 64; key++) {
        float4 kk = kvs[key];                           // broadcast: conflict-free
        float4 vv = kvs[256 + key];
        #pragma unroll
        for (int r = 0; r < 8; r++) {
            float s = qr[r].x * kk.x + qr[r].y * kk.y + qr[r].z * kk.z + qr[r].w * kk.w;
            float p = __builtin_amdgcn_exp2f(s);        // bare v_exp_f32
            lr[r] += p;
            ar[r].x += p * vv.x; ar[r].y += p * vv.y;
            ar[r].z += p * vv.z; ar[r].w += p * vv.w;
        }
    }
    if (w > 0) {                                        // wave-uniform branch
        int base = (w - 1) * 512;
        #pragma unroll
        for (int r = 0; r < 8; r++) {
            pa[base + r * 64 + lane] = ar[r];           // natural float4 stride
            pl[base + r * 64 + lane] = lr[r];
        }
    }
    __syncthreads();
    if (w == 0) {
        float* slab = o_part + (bh * 4 + chunk) * 5120; // shared slab, disjoint rows
        #pragma unroll
        for (int r = 0; r < 8; r++) {
            int nl = r * 64 + lane;
            float4 s = ar[r]; float ls = lr[r];
            #pragma unroll
            for (int j = 0; j < 3; j++) {
                float4 p4 = pa[j * 512 + nl];
                s.x += p4.x; s.y += p4.y; s.z += p4.z; s.w += p4.w;
                ls += pl[j * 512 + nl];
            }
            int n = rh * 512 + nl;
            *(float4*)&slab[n * 4] = s;
            slab[4096 + n] = ls;
        }
    }
}

// ---------------- Kernel D: combine partials + o @ w_proj + BN + max-unpool ---------
__global__ __launch_bounds__(256) void proj_kernel(const float* __restrict__ o_part,
                                                   const float* __restrict__ w_proj,
                                                   const float* __restrict__ gamma,
                                                   const float* __restrict__ beta,
                                                   const float* __restrict__ mean,
                                                   const float* __restrict__ var,
                                                   const int* __restrict__ idx,
                                                   float* __restrict__ out) {
    __shared__ float ws[64 * 64];                       // w_proj
    int b = blockIdx.x >> 5, hp = blockIdx.x & 31;
    int tid = threadIdx.x;
    for (int i = tid; i < 4096; i += 256) ws[i] = w_proj[i];
    int wp = tid & 31, cg = tid >> 5;                   // 8 c-groups x 32 wp
    int n = hp * 32 + wp;
    float oreg[64];                                     // normalized o row in registers
    #pragma unroll
    for (int h = 0; h < 16; h++) {
        const float* base = o_part + ((b * 16 + h) * 4) * 5120;
        float4 osum = {0, 0, 0, 0}; float lsum = 0.f;
        #pragma unroll
        for (int c = 0; c < 4; c++) {
            const float* sl = base + c * 5120;
            float4 t4 = *(const float4*)&sl[n * 4];     // coalesced across wp lanes
            osum.x += t4.x; osum.y += t4.y; osum.z += t4.z; osum.w += t4.w;
            lsum += sl[4096 + n];
        }
        float r = 1.f / lsum;
        oreg[h * 4 + 0] = osum.x * r; oreg[h * 4 + 1] = osum.y * r;
        oreg[h * 4 + 2] = osum.z * r; oreg[h * 4 + 3] = osum.w * r;
    }
    __syncthreads();
    #pragma unroll
    for (int cc = 0; cc < 8; cc++) {
        int c = cg + 8 * cc;                            // 8 distinct banks -> conflict-free
        float acc = 0.f;
        #pragma unroll
        for (int a = 0; a < 64; a++) acc += oreg[a] * ws[a * 64 + c];
        float inv = gamma[c] * rsqrtf(var[c] + 1e-5f);
        float val = acc * inv + (beta[c] - mean[c] * inv);
        int id = idx[((b * 64 + c) * 32 + hp) * 32 + wp];
        int base = ((b * 64 + c) * 64 + 2 * hp) * 64 + 2 * wp;
        float2 r0 = { id == 0 ? val : 0.f, id == 1 ? val : 0.f };
        float2 r1 = { id == 2 ? val : 0.f, id == 3 ? val : 0.f };
        *(float2*)&out[base] = r0;                      // row 2hp,   cols 2wp..2wp+1
        *(float2*)&out[base + 64] = r1;                 // row 2hp+1
    }
}

extern "C" void kernel_launch(void* const* d_in, const int* in_sizes, int n_in,
                              void* d_out, int out_size, void* d_ws, size_t ws_size,
                              hipStream_t stream) {
    const float* x      = (const float*)d_in[0];
    const float* w_qkv  = (const float*)d_in[1];
    const float* w_proj = (const float*)d_in[2];
    const float* gamma  = (const float*)d_in[3];
    const float* beta   = (const float*)d_in[4];
    const float* bn_mean= (const float*)d_in[5];
    const float* bn_var = (const float*)d_in[6];
    float* out = (float*)d_out;

    const int SEG = 524288;                             // 8*1024*64
    float* ws = (float*)d_ws;
    float* t      = ws;
    int*   idx    = (int*)(ws + SEG);
    float* q      = ws + 2 * SEG;
    float* k      = ws + 3 * SEG;
    float* v      = ws + 4 * SEG;
    float* o_part = ws + 5 * SEG;                       // 512 * 5120 floats = 10.5 MB

    pool_kernel<<<2048, 256, 0, stream>>>(x, t, idx);
    qkv_kernel<<<512, 192, 0, stream>>>(t, w_qkv, q, k, v);
    attn_kernel<<<1024, 256, 0, stream>>>(q, k, v, o_part);
    proj_kernel<<<256, 256, 0, stream>>>(o_part, w_proj, gamma, beta, bn_mean, bn_var, idx, out);
}

// Round 6
// 139.385 us; speedup vs baseline: 1.9037x; 1.0707x over previous
//
#include <hip/hip_runtime.h>
#include <hip/hip_bf16.h>

// Problem: B=8, C=DIM=64, H=W=64 -> pooled 32x32 (N=1024 tokens), 16 heads x d=4.
// ws layout (floats):
//   t[524288] | idx[524288 ints] | q[524288] | k[524288] | v[524288]
//   | o_part[512 * 5120]   (per (bh,chunk) slab: [0,4096)=numerator float4 per n,
//                           [4096,5120)=denominator per n)
// q/k/v layout: (B, H=16, N=1024, D=4) contiguous -> per (b,h) a 4096-float slab.

typedef float v2f __attribute__((ext_vector_type(2)));

// ---------------- Kernel A: 2x2 maxpool + argmax ----------------
__global__ __launch_bounds__(256) void pool_kernel(const float* __restrict__ x,
                                                   float* __restrict__ t,
                                                   int* __restrict__ idx) {
    int g = blockIdx.x * 256 + threadIdx.x;            // covers 8*64*32*32 = 524288
    int wp = g & 31, hp = (g >> 5) & 31, c = (g >> 10) & 63, b = g >> 16;
    const float* px = x + (((b * 64 + c) * 64 + 2 * hp) * 64 + 2 * wp);
    float2 r0 = *(const float2*)px;
    float2 r1 = *(const float2*)(px + 64);
    float best = r0.x; int bi = 0;                      // first-max semantics (strict >)
    if (r0.y > best) { best = r0.y; bi = 1; }
    if (r1.x > best) { best = r1.x; bi = 2; }
    if (r1.y > best) { best = r1.y; bi = 3; }
    int n = hp * 32 + wp;
    t[(b * 1024 + n) * 64 + c] = best;
    idx[g] = bi;                                        // layout (b,c,hp,wp)
}

// ---------------- Kernel B: qkv = t @ w_qkv, scatter to (B,H,N,4) ----------------
__global__ __launch_bounds__(192) void qkv_kernel(const float* __restrict__ t,
                                                  const float* __restrict__ w_qkv,
                                                  float* __restrict__ q,
                                                  float* __restrict__ k,
                                                  float* __restrict__ v) {
    __shared__ float trow[16 * 64];                     // 16 token rows
    int tid = threadIdx.x;                              // 0..191 (j = output column)
    int row0 = blockIdx.x * 16;
    for (int i = tid; i < 1024; i += 192) trow[i] = t[row0 * 64 + i];
    float wcol[64];                                     // my w_qkv column, in registers
    #pragma unroll
    for (int c = 0; c < 64; c++) wcol[c] = w_qkv[c * 192 + tid];
    __syncthreads();
    int s = tid >> 6, h = (tid >> 2) & 15, d = tid & 3;
    float* dst = (s == 0) ? q : (s == 1) ? k : v;
    for (int r = 0; r < 16; r++) {
        const float4* tr = (const float4*)&trow[r * 64];
        float acc = 0.f;
        #pragma unroll
        for (int c4 = 0; c4 < 16; c4++) {
            float4 tv = tr[c4];                         // LDS broadcast (all lanes same addr)
            acc += tv.x * wcol[c4 * 4] + tv.y * wcol[c4 * 4 + 1]
                 + tv.z * wcol[c4 * 4 + 2] + tv.w * wcol[c4 * 4 + 3];
        }
        int ng = row0 + r, b = ng >> 10, n = ng & 1023;
        dst[((b * 16 + h) * 1024 + n) * 4 + d] = acc;
    }
}

// ---------------- Kernel C: flash attention, row-pair-packed fp32 (v_pk_fma_f32) ----
// Structure identical to R5 (128 bh * 4 key-chunks * 2 row-halves, 4-way per-wave key
// split, R=8 rows/thread). R5 measurement showed the SIMD issue port saturated:
// VALUBusy 69% = main-VALU 144cyc / (144 + 64 trans) per iter -> occupancy can't help.
// This version packs the 8 rows as 4 float2 row-PAIRS so dot/l/accumulate use packed
// fp32 VOP3P ops (36 pk vs 72 scalar per key) at NEUTRAL register cost (packing keys
// instead would double accumulator VGPRs). exp stays scalar (quarter-rate trans).
__global__ __launch_bounds__(256) void attn_kernel(const float* __restrict__ q,
                                                   const float* __restrict__ k,
                                                   const float* __restrict__ v,
                                                   float* __restrict__ o_part) {
    __shared__ float4 kvs[512];                         // [0,256)=K chunk, [256,512)=V chunk
    __shared__ float4 pa[3 * 512];                      // waves 1..3 numerator partials
    __shared__ float  pl[3 * 512];                      // waves 1..3 denominator partials
    int bh = blockIdx.x >> 3;
    int chunk = (blockIdx.x >> 1) & 3;                  // key chunk (256 keys)
    int rh = blockIdx.x & 1;                            // row half (512 rows)
    int tid = threadIdx.x;
    const float4* kp = (const float4*)(k + bh * 4096) + chunk * 256;
    const float4* vp = (const float4*)(v + bh * 4096) + chunk * 256;
    kvs[tid] = kp[tid];
    kvs[256 + tid] = vp[tid];
    int w = tid >> 6;                                   // wave id 0..3 (wave-uniform)
    int lane = tid & 63;
    const float C1 = 0.5f * 1.44269504088896f;          // scale * log2(e), folded into q
    const float4* qp = (const float4*)(q + bh * 4096) + rh * 512;
    // row-pair j holds rows (2j)*64+lane and (2j+1)*64+lane
    v2f q2x[4], q2y[4], q2z[4], q2w[4];
    #pragma unroll
    for (int j = 0; j < 4; j++) {
        float4 qa = qp[(2 * j) * 64 + lane];            // coalesced
        float4 qb = qp[(2 * j + 1) * 64 + lane];
        q2x[j] = (v2f){qa.x * C1, qb.x * C1};
        q2y[j] = (v2f){qa.y * C1, qb.y * C1};
        q2z[j] = (v2f){qa.z * C1, qb.z * C1};
        q2w[j] = (v2f){qa.w * C1, qb.w * C1};
    }
    __syncthreads();
    v2f l2[4], a2x[4], a2y[4], a2z[4], a2w[4];
    #pragma unroll
    for (int j = 0; j < 4; j++) {
        l2[j] = (v2f)(0.f); a2x[j] = (v2f)(0.f); a2y[j] = (v2f)(0.f);
        a2z[j] = (v2f)(0.f); a2w[j] = (v2f)(0.f);
    }
    int k0 = w * 64;
    #pragma unroll 2
    for (int key = k0; key < k0 + 64; key++) {
        float4 kk = kvs[key];                           // broadcast: conflict-free
        float4 vv = kvs[256 + key];
        v2f kx = (v2f){kk.x, kk.x}, ky = (v2f){kk.y, kk.y};
        v2f kz = (v2f){kk.z, kk.z}, kw = (v2f){kk.w, kk.w};
        v2f vx = (v2f){vv.x, vv.x}, vy = (v2f){vv.y, vv.y};
        v2f vz = (v2f){vv.z, vv.z}, vw = (v2f){vv.w, vv.w};
        #pragma unroll
        for (int j = 0; j < 4; j++) {
            v2f s2 = __builtin_elementwise_fma(q2x[j], kx,
                     __builtin_elementwise_fma(q2y[j], ky,
                     __builtin_elementwise_fma(q2z[j], kz, q2w[j] * kw)));
            v2f p2;
            p2.x = __builtin_amdgcn_exp2f(s2.x);        // bare v_exp_f32 (trans pipe)
            p2.y = __builtin_amdgcn_exp2f(s2.y);
            l2[j] += p2;                                // v_pk_add_f32
            a2x[j] = __builtin_elementwise_fma(p2, vx, a2x[j]);  // v_pk_fma_f32
            a2y[j] = __builtin_elementwise_fma(p2, vy, a2y[j]);
            a2z[j] = __builtin_elementwise_fma(p2, vz, a2z[j]);
            a2w[j] = __builtin_elementwise_fma(p2, vw, a2w[j]);
        }
    }
    if (w > 0) {                                        // wave-uniform branch
        int base = (w - 1) * 512;
        #pragma unroll
        for (int r = 0; r < 8; r++) {
            int j = r >> 1, h = r & 1;
            float4 ar = { h ? a2x[j].y : a2x[j].x, h ? a2y[j].y : a2y[j].x,
                          h ? a2z[j].y : a2z[j].x, h ? a2w[j].y : a2w[j].x };
            pa[base + r * 64 + lane] = ar;              // natural float4 stride
            pl[base + r * 64 + lane] = h ? l2[j].y : l2[j].x;
        }
    }
    __syncthreads();
    if (w == 0) {
        float* slab = o_part + (bh * 4 + chunk) * 5120; // shared slab, disjoint rows
        #pragma unroll
        for (int r = 0; r < 8; r++) {
            int j = r >> 1, h = r & 1;
            int nl = r * 64 + lane;
            float4 s = { h ? a2x[j].y : a2x[j].x, h ? a2y[j].y : a2y[j].x,
                         h ? a2z[j].y : a2z[j].x, h ? a2w[j].y : a2w[j].x };
            float ls = h ? l2[j].y : l2[j].x;
            #pragma unroll
            for (int jj = 0; jj < 3; jj++) {
                float4 p4 = pa[jj * 512 + nl];
                s.x += p4.x; s.y += p4.y; s.z += p4.z; s.w += p4.w;
                ls += pl[jj * 512 + nl];
            }
            int n = rh * 512 + nl;
            *(float4*)&slab[n * 4] = s;
            slab[4096 + n] = ls;
        }
    }
}

// ---------------- Kernel D: combine partials + o @ w_proj + BN + max-unpool ---------
__global__ __launch_bounds__(256) void proj_kernel(const float* __restrict__ o_part,
                                                   const float* __restrict__ w_proj,
                                                   const float* __restrict__ gamma,
                                                   const float* __restrict__ beta,
                                                   const float* __restrict__ mean,
                                                   const float* __restrict__ var,
                                                   const int* __restrict__ idx,
                                                   float* __restrict__ out) {
    __shared__ float ws[64 * 64];                       // w_proj
    int b = blockIdx.x >> 5, hp = blockIdx.x & 31;
    int tid = threadIdx.x;
    for (int i = tid; i < 4096; i += 256) ws[i] = w_proj[i];
    int wp = tid & 31, cg = tid >> 5;                   // 8 c-groups x 32 wp
    int n = hp * 32 + wp;
    float oreg[64];                                     // normalized o row in registers
    #pragma unroll
    for (int h = 0; h < 16; h++) {
        const float* base = o_part + ((b * 16 + h) * 4) * 5120;
        float4 osum = {0, 0, 0, 0}; float lsum = 0.f;
        #pragma unroll
        for (int c = 0; c < 4; c++) {
            const float* sl = base + c * 5120;
            float4 t4 = *(const float4*)&sl[n * 4];     // coalesced across wp lanes
            osum.x += t4.x; osum.y += t4.y; osum.z += t4.z; osum.w += t4.w;
            lsum += sl[4096 + n];
        }
        float r = 1.f / lsum;
        oreg[h * 4 + 0] = osum.x * r; oreg[h * 4 + 1] = osum.y * r;
        oreg[h * 4 + 2] = osum.z * r; oreg[h * 4 + 3] = osum.w * r;
    }
    __syncthreads();
    #pragma unroll
    for (int cc = 0; cc < 8; cc++) {
        int c = cg + 8 * cc;                            // 8 distinct banks -> conflict-free
        float acc = 0.f;
        #pragma unroll
        for (int a = 0; a < 64; a++) acc += oreg[a] * ws[a * 64 + c];
        float inv = gamma[c] * rsqrtf(var[c] + 1e-5f);
        float val = acc * inv + (beta[c] - mean[c] * inv);
        int id = idx[((b * 64 + c) * 32 + hp) * 32 + wp];
        int base = ((b * 64 + c) * 64 + 2 * hp) * 64 + 2 * wp;
        float2 r0 = { id == 0 ? val : 0.f, id == 1 ? val : 0.f };
        float2 r1 = { id == 2 ? val : 0.f, id == 3 ? val : 0.f };
        *(float2*)&out[base] = r0;                      // row 2hp,   cols 2wp..2wp+1
        *(float2*)&out[base + 64] = r1;                 // row 2hp+1
    }
}

extern "C" void kernel_launch(void* const* d_in, const int* in_sizes, int n_in,
                              void* d_out, int out_size, void* d_ws, size_t ws_size,
                              hipStream_t stream) {
    const float* x      = (const float*)d_in[0];
    const float* w_qkv  = (const float*)d_in[1];
    const float* w_proj = (const float*)d_in[2];
    const float* gamma  = (const float*)d_in[3];
    const float* beta   = (const float*)d_in[4];
    const float* bn_mean= (const float*)d_in[5];
    const float* bn_var = (const float*)d_in[6];
    float* out = (float*)d_out;

    const int SEG = 524288;                             // 8*1024*64
    float* ws = (float*)d_ws;
    float* t      = ws;
    int*   idx    = (int*)(ws + SEG);
    float* q      = ws + 2 * SEG;
    float* k      = ws + 3 * SEG;
    float* v      = ws + 4 * SEG;
    float* o_part = ws + 5 * SEG;                       // 512 * 5120 floats = 10.5 MB

    pool_kernel<<<2048, 256, 0, stream>>>(x, t, idx);
    qkv_kernel<<<512, 192, 0, stream>>>(t, w_qkv, q, k, v);
    attn_kernel<<<1024, 256, 0, stream>>>(q, k, v, o_part);
    proj_kernel<<<256, 256, 0, stream>>>(o_part, w_proj, gamma, beta, bn_mean, bn_var, idx, out);
}

// Round 7
// 138.236 us; speedup vs baseline: 1.9196x; 1.0083x over previous
//
#include <hip/hip_runtime.h>
#include <hip/hip_bf16.h>

// Problem: B=8, C=DIM=64, H=W=64 -> pooled 32x32 (N=1024 tokens), 16 heads x d=4.
// ws layout (floats):
//   t[524288] | idx[524288 ints] | q[524288] | k[524288] | v[524288]
//   | o_part[512 * 5120]   (per (bh,chunk) slab: [0,4096)=numerator float4 per n,
//                           [4096,5120)=denominator per n)
// q/k/v layout: (B, H=16, N=1024, D=4) contiguous -> per (b,h) a 4096-float slab.

typedef float v2f __attribute__((ext_vector_type(2)));

// ---------------- Kernel A: 2x2 maxpool + argmax ----------------
__global__ __launch_bounds__(256) void pool_kernel(const float* __restrict__ x,
                                                   float* __restrict__ t,
                                                   int* __restrict__ idx) {
    int g = blockIdx.x * 256 + threadIdx.x;            // covers 8*64*32*32 = 524288
    int wp = g & 31, hp = (g >> 5) & 31, c = (g >> 10) & 63, b = g >> 16;
    const float* px = x + (((b * 64 + c) * 64 + 2 * hp) * 64 + 2 * wp);
    float2 r0 = *(const float2*)px;
    float2 r1 = *(const float2*)(px + 64);
    float best = r0.x; int bi = 0;                      // first-max semantics (strict >)
    if (r0.y > best) { best = r0.y; bi = 1; }
    if (r1.x > best) { best = r1.x; bi = 2; }
    if (r1.y > best) { best = r1.y; bi = 3; }
    int n = hp * 32 + wp;
    t[(b * 1024 + n) * 64 + c] = best;
    idx[g] = bi;                                        // layout (b,c,hp,wp)
}

// ---------------- Kernel B: qkv = t @ w_qkv, scatter to (B,H,N,4) ----------------
__global__ __launch_bounds__(192) void qkv_kernel(const float* __restrict__ t,
                                                  const float* __restrict__ w_qkv,
                                                  float* __restrict__ q,
                                                  float* __restrict__ k,
                                                  float* __restrict__ v) {
    __shared__ float trow[16 * 64];                     // 16 token rows
    int tid = threadIdx.x;                              // 0..191 (j = output column)
    int row0 = blockIdx.x * 16;
    for (int i = tid; i < 1024; i += 192) trow[i] = t[row0 * 64 + i];
    float wcol[64];                                     // my w_qkv column, in registers
    #pragma unroll
    for (int c = 0; c < 64; c++) wcol[c] = w_qkv[c * 192 + tid];
    __syncthreads();
    int s = tid >> 6, h = (tid >> 2) & 15, d = tid & 3;
    float* dst = (s == 0) ? q : (s == 1) ? k : v;
    for (int r = 0; r < 16; r++) {
        const float4* tr = (const float4*)&trow[r * 64];
        float acc = 0.f;
        #pragma unroll
        for (int c4 = 0; c4 < 16; c4++) {
            float4 tv = tr[c4];                         // LDS broadcast (all lanes same addr)
            acc += tv.x * wcol[c4 * 4] + tv.y * wcol[c4 * 4 + 1]
                 + tv.z * wcol[c4 * 4 + 2] + tv.w * wcol[c4 * 4 + 3];
        }
        int ng = row0 + r, b = ng >> 10, n = ng & 1023;
        dst[((b * 16 + h) * 1024 + n) * 4 + d] = acc;
    }
}

// ---------------- Kernel C: flash attention, packed fp32 + 4-key software pipeline --
// Structure identical to R6 (128 bh * 4 key-chunks * 2 row-halves, 4-way per-wave key
// split, R=8 rows/thread as 4 float2 row-pairs, v_pk_fma_f32 math, bare v_exp_f32).
// R6 was ~2x over its issue-cycle floor -> per-key ds_read->use dependency stalls.
// This version batches 4 keys: issue all 8 ds_read_b128 up-front, then ~144 cyc of
// independent math covers the LDS latency within a single wave.
__global__ __launch_bounds__(256) void attn_kernel(const float* __restrict__ q,
                                                   const float* __restrict__ k,
                                                   const float* __restrict__ v,
                                                   float* __restrict__ o_part) {
    __shared__ float4 kvs[512];                         // [0,256)=K chunk, [256,512)=V chunk
    __shared__ float4 pa[3 * 512];                      // waves 1..3 numerator partials
    __shared__ float  pl[3 * 512];                      // waves 1..3 denominator partials
    int bh = blockIdx.x >> 3;
    int chunk = (blockIdx.x >> 1) & 3;                  // key chunk (256 keys)
    int rh = blockIdx.x & 1;                            // row half (512 rows)
    int tid = threadIdx.x;
    const float4* kp = (const float4*)(k + bh * 4096) + chunk * 256;
    const float4* vp = (const float4*)(v + bh * 4096) + chunk * 256;
    kvs[tid] = kp[tid];
    kvs[256 + tid] = vp[tid];
    int w = tid >> 6;                                   // wave id 0..3 (wave-uniform)
    int lane = tid & 63;
    const float C1 = 0.5f * 1.44269504088896f;          // scale * log2(e), folded into q
    const float4* qp = (const float4*)(q + bh * 4096) + rh * 512;
    // row-pair j holds rows (2j)*64+lane and (2j+1)*64+lane
    v2f q2x[4], q2y[4], q2z[4], q2w[4];
    #pragma unroll
    for (int j = 0; j < 4; j++) {
        float4 qa = qp[(2 * j) * 64 + lane];            // coalesced
        float4 qb = qp[(2 * j + 1) * 64 + lane];
        q2x[j] = (v2f){qa.x * C1, qb.x * C1};
        q2y[j] = (v2f){qa.y * C1, qb.y * C1};
        q2z[j] = (v2f){qa.z * C1, qb.z * C1};
        q2w[j] = (v2f){qa.w * C1, qb.w * C1};
    }
    __syncthreads();
    v2f l2[4], a2x[4], a2y[4], a2z[4], a2w[4];
    #pragma unroll
    for (int j = 0; j < 4; j++) {
        l2[j] = (v2f)(0.f); a2x[j] = (v2f)(0.f); a2y[j] = (v2f)(0.f);
        a2z[j] = (v2f)(0.f); a2w[j] = (v2f)(0.f);
    }
    int k0 = w * 64;
    for (int kb = k0; kb < k0 + 64; kb += 4) {          // 4-key software-pipelined batch
        float4 kk[4], vv[4];
        #pragma unroll
        for (int u = 0; u < 4; u++) {                   // 8 independent ds_read_b128
            kk[u] = kvs[kb + u];
            vv[u] = kvs[256 + kb + u];
        }
        #pragma unroll
        for (int u = 0; u < 4; u++) {
            v2f kx = (v2f){kk[u].x, kk[u].x}, ky = (v2f){kk[u].y, kk[u].y};
            v2f kz = (v2f){kk[u].z, kk[u].z}, kw = (v2f){kk[u].w, kk[u].w};
            v2f vx = (v2f){vv[u].x, vv[u].x}, vy = (v2f){vv[u].y, vv[u].y};
            v2f vz = (v2f){vv[u].z, vv[u].z}, vw = (v2f){vv[u].w, vv[u].w};
            #pragma unroll
            for (int j = 0; j < 4; j++) {
                v2f s2 = __builtin_elementwise_fma(q2x[j], kx,
                         __builtin_elementwise_fma(q2y[j], ky,
                         __builtin_elementwise_fma(q2z[j], kz, q2w[j] * kw)));
                v2f p2;
                p2.x = __builtin_amdgcn_exp2f(s2.x);    // bare v_exp_f32 (trans pipe)
                p2.y = __builtin_amdgcn_exp2f(s2.y);
                l2[j] += p2;                            // v_pk_add_f32
                a2x[j] = __builtin_elementwise_fma(p2, vx, a2x[j]);  // v_pk_fma_f32
                a2y[j] = __builtin_elementwise_fma(p2, vy, a2y[j]);
                a2z[j] = __builtin_elementwise_fma(p2, vz, a2z[j]);
                a2w[j] = __builtin_elementwise_fma(p2, vw, a2w[j]);
            }
        }
    }
    if (w > 0) {                                        // wave-uniform branch
        int base = (w - 1) * 512;
        #pragma unroll
        for (int r = 0; r < 8; r++) {
            int j = r >> 1, h = r & 1;
            float4 ar = { h ? a2x[j].y : a2x[j].x, h ? a2y[j].y : a2y[j].x,
                          h ? a2z[j].y : a2z[j].x, h ? a2w[j].y : a2w[j].x };
            pa[base + r * 64 + lane] = ar;              // natural float4 stride
            pl[base + r * 64 + lane] = h ? l2[j].y : l2[j].x;
        }
    }
    __syncthreads();
    if (w == 0) {
        float* slab = o_part + (bh * 4 + chunk) * 5120; // shared slab, disjoint rows
        #pragma unroll
        for (int r = 0; r < 8; r++) {
            int j = r >> 1, h = r & 1;
            int nl = r * 64 + lane;
            float4 s = { h ? a2x[j].y : a2x[j].x, h ? a2y[j].y : a2y[j].x,
                         h ? a2z[j].y : a2z[j].x, h ? a2w[j].y : a2w[j].x };
            float ls = h ? l2[j].y : l2[j].x;
            #pragma unroll
            for (int jj = 0; jj < 3; jj++) {
                float4 p4 = pa[jj * 512 + nl];
                s.x += p4.x; s.y += p4.y; s.z += p4.z; s.w += p4.w;
                ls += pl[jj * 512 + nl];
            }
            int n = rh * 512 + nl;
            *(float4*)&slab[n * 4] = s;
            slab[4096 + n] = ls;
        }
    }
}

// ---------------- Kernel D: combine partials + o @ w_proj + BN + max-unpool ---------
__global__ __launch_bounds__(256) void proj_kernel(const float* __restrict__ o_part,
                                                   const float* __restrict__ w_proj,
                                                   const float* __restrict__ gamma,
                                                   const float* __restrict__ beta,
                                                   const float* __restrict__ mean,
                                                   const float* __restrict__ var,
                                                   const int* __restrict__ idx,
                                                   float* __restrict__ out) {
    __shared__ float ws[64 * 64];                       // w_proj
    int b = blockIdx.x >> 5, hp = blockIdx.x & 31;
    int tid = threadIdx.x;
    for (int i = tid; i < 4096; i += 256) ws[i] = w_proj[i];
    int wp = tid & 31, cg = tid >> 5;                   // 8 c-groups x 32 wp
    int n = hp * 32 + wp;
    float oreg[64];                                     // normalized o row in registers
    #pragma unroll
    for (int h = 0; h < 16; h++) {
        const float* base = o_part + ((b * 16 + h) * 4) * 5120;
        float4 osum = {0, 0, 0, 0}; float lsum = 0.f;
        #pragma unroll
        for (int c = 0; c < 4; c++) {
            const float* sl = base + c * 5120;
            float4 t4 = *(const float4*)&sl[n * 4];     // coalesced across wp lanes
            osum.x += t4.x; osum.y += t4.y; osum.z += t4.z; osum.w += t4.w;
            lsum += sl[4096 + n];
        }
        float r = 1.f / lsum;
        oreg[h * 4 + 0] = osum.x * r; oreg[h * 4 + 1] = osum.y * r;
        oreg[h * 4 + 2] = osum.z * r; oreg[h * 4 + 3] = osum.w * r;
    }
    __syncthreads();
    #pragma unroll
    for (int cc = 0; cc < 8; cc++) {
        int c = cg + 8 * cc;                            // 8 distinct banks -> conflict-free
        float acc = 0.f;
        #pragma unroll
        for (int a = 0; a < 64; a++) acc += oreg[a] * ws[a * 64 + c];
        float inv = gamma[c] * rsqrtf(var[c] + 1e-5f);
        float val = acc * inv + (beta[c] - mean[c] * inv);
        int id = idx[((b * 64 + c) * 32 + hp) * 32 + wp];
        int base = ((b * 64 + c) * 64 + 2 * hp) * 64 + 2 * wp;
        float2 r0 = { id == 0 ? val : 0.f, id == 1 ? val : 0.f };
        float2 r1 = { id == 2 ? val : 0.f, id == 3 ? val : 0.f };
        *(float2*)&out[base] = r0;                      // row 2hp,   cols 2wp..2wp+1
        *(float2*)&out[base + 64] = r1;                 // row 2hp+1
    }
}

extern "C" void kernel_launch(void* const* d_in, const int* in_sizes, int n_in,
                              void* d_out, int out_size, void* d_ws, size_t ws_size,
                              hipStream_t stream) {
    const float* x      = (const float*)d_in[0];
    const float* w_qkv  = (const float*)d_in[1];
    const float* w_proj = (const float*)d_in[2];
    const float* gamma  = (const float*)d_in[3];
    const float* beta   = (const float*)d_in[4];
    const float* bn_mean= (const float*)d_in[5];
    const float* bn_var = (const float*)d_in[6];
    float* out = (float*)d_out;

    const int SEG = 524288;                             // 8*1024*64
    float* ws = (float*)d_ws;
    float* t      = ws;
    int*   idx    = (int*)(ws + SEG);
    float* q      = ws + 2 * SEG;
    float* k      = ws + 3 * SEG;
    float* v      = ws + 4 * SEG;
    float* o_part = ws + 5 * SEG;                       // 512 * 5120 floats = 10.5 MB

    pool_kernel<<<2048, 256, 0, stream>>>(x, t, idx);
    qkv_kernel<<<512, 192, 0, stream>>>(t, w_qkv, q, k, v);
    attn_kernel<<<1024, 256, 0, stream>>>(q, k, v, o_part);
    proj_kernel<<<256, 256, 0, stream>>>(o_part, w_proj, gamma, beta, bn_mean, bn_var, idx, out);
}

// Round 10
// 132.859 us; speedup vs baseline: 1.9973x; 1.0405x over previous
//
#include <hip/hip_runtime.h>
#include <hip/hip_bf16.h>

// Problem: B=8, C=DIM=64, H=W=64 -> pooled 32x32 (N=1024 tokens), 16 heads x d=4.
// ws layout (floats): t[524288] | idx[524288 ints] | q[524288] | k[524288] | v[524288]
//                     | o[524288] (normalized attention output, (B,N,64))
// q/k/v layout: (B, H=16, N=1024, D=4) contiguous -> per (b,h) a 4096-float slab.

typedef float    v2f   __attribute__((ext_vector_type(2)));
typedef float    f32x4 __attribute__((ext_vector_type(4)));
typedef _Float16 f16x8 __attribute__((ext_vector_type(8)));

// ---------------- Kernel A: 2x2 maxpool + argmax ----------------
__global__ __launch_bounds__(256) void pool_kernel(const float* __restrict__ x,
                                                   float* __restrict__ t,
                                                   int* __restrict__ idx) {
    int g = blockIdx.x * 256 + threadIdx.x;            // covers 8*64*32*32 = 524288
    int wp = g & 31, hp = (g >> 5) & 31, c = (g >> 10) & 63, b = g >> 16;
    const float* px = x + (((b * 64 + c) * 64 + 2 * hp) * 64 + 2 * wp);
    float2 r0 = *(const float2*)px;
    float2 r1 = *(const float2*)(px + 64);
    float best = r0.x; int bi = 0;                      // first-max semantics (strict >)
    if (r0.y > best) { best = r0.y; bi = 1; }
    if (r1.x > best) { best = r1.x; bi = 2; }
    if (r1.y > best) { best = r1.y; bi = 3; }
    int n = hp * 32 + wp;
    t[(b * 1024 + n) * 64 + c] = best;
    idx[g] = bi;                                        // layout (b,c,hp,wp)
}

// ---------------- Kernel B: qkv = t @ w_qkv, scatter to (B,H,N,4) ----------------
__global__ __launch_bounds__(192) void qkv_kernel(const float* __restrict__ t,
                                                  const float* __restrict__ w_qkv,
                                                  float* __restrict__ q,
                                                  float* __restrict__ k,
                                                  float* __restrict__ v) {
    __shared__ float trow[16 * 64];                     // 16 token rows
    int tid = threadIdx.x;                              // 0..191 (j = output column)
    int row0 = blockIdx.x * 16;
    for (int i = tid; i < 1024; i += 192) trow[i] = t[row0 * 64 + i];
    float wcol[64];                                     // my w_qkv column, in registers
    #pragma unroll
    for (int c = 0; c < 64; c++) wcol[c] = w_qkv[c * 192 + tid];
    __syncthreads();
    int s = tid >> 6, h = (tid >> 2) & 15, d = tid & 3;
    float* dst = (s == 0) ? q : (s == 1) ? k : v;
    for (int r = 0; r < 16; r++) {
        const float4* tr = (const float4*)&trow[r * 64];
        float acc = 0.f;
        #pragma unroll
        for (int c4 = 0; c4 < 16; c4++) {
            float4 tv = tr[c4];                         // LDS broadcast (all lanes same addr)
            acc += tv.x * wcol[c4 * 4] + tv.y * wcol[c4 * 4 + 1]
                 + tv.z * wcol[c4 * 4 + 2] + tv.w * wcol[c4 * 4 + 3];
        }
        int ng = row0 + r, b = ng >> 10, n = ng & 1023;
        dst[((b * 16 + h) * 1024 + n) * 4 + d] = acc;
    }
}

// ---------------- Kernel C: MFMA attention, Markidis-exact S, LDS epilogue ----------
// R9 post-mortem: f16 quantization of Q,K put first-launch absmax at 0.0586 (thr
// 0.0466). Fix: hi/lo f16 split of both Q and K packed into ONE 16x16x32 MFMA's
// unused K-slots. (quad,j) slots of A and B pair identically under any consistent
// k-mapping, so with
//   A: quad0={qh|qh}, quad1={ql|ql}, quads2-3=0
//   B: quads0-1={kh[0..3]|kl[0..3]}, quads2-3=0
// S = (qh+ql)(kh+kl) -- exact to ~2^-22 relative, fp32-level like rounds 1-7.
// Epilogue = R9's LDS reduction (no cross-lane intrinsics; R8's shfl epilogue was
// the replay-divergence suspect). Reduction scratch aliases dead K/V staging.
// grid = 128 bh * 8 row-blocks of 128 rows; block = 4 waves, wave = 2 strips of 16.
__global__ __launch_bounds__(256) void attn_kernel(const float* __restrict__ q,
                                                   const float* __restrict__ k,
                                                   const float* __restrict__ v,
                                                   float* __restrict__ o) {
    __shared__ __align__(16) unsigned char smem[32768];
    f16x8*  Kh2  = (f16x8*)smem;                        // [0,16384): 1024 keys {hi4|lo4}
    float4* Vs   = (float4*)(smem + 16384);             // [16384,32768): 1024 vals fp32
    float4* red4 = (float4*)smem;                       // epilogue alias [0,16384)
    float*  redl = (float*)(smem + 16384);              // epilogue alias [16384,20480)
    int bh = blockIdx.x >> 3;
    int row0 = (blockIdx.x & 7) * 128;
    int tid = threadIdx.x;
    const float4* kp4 = (const float4*)(k + bh * 4096);
    const float4* vp4 = (const float4*)(v + bh * 4096);
    #pragma unroll
    for (int i = 0; i < 4; i++) {                       // stage K (hi/lo f16) + V (fp32)
        int ix = i * 256 + tid;
        float4 kf = kp4[ix];
        f16x8 kk;
        kk[0] = (_Float16)kf.x; kk[4] = (_Float16)(kf.x - (float)kk[0]);
        kk[1] = (_Float16)kf.y; kk[5] = (_Float16)(kf.y - (float)kk[1]);
        kk[2] = (_Float16)kf.z; kk[6] = (_Float16)(kf.z - (float)kk[2]);
        kk[3] = (_Float16)kf.w; kk[7] = (_Float16)(kf.w - (float)kk[3]);
        Kh2[ix] = kk;
        Vs[ix] = vp4[ix];
    }
    int w = tid >> 6, lane = tid & 63;
    int c = lane & 15, quad = lane >> 4;
    const float C1 = 0.5f * 1.44269504088896f;          // scale * log2(e), folded into Q
    const float4* qp4 = (const float4*)(q + bh * 4096);
    f16x8 afrag[2];
    #pragma unroll
    for (int s = 0; s < 2; s++) {                       // A-frags for my 2 row strips
        int rowg = row0 + w * 32 + s * 16 + c;
        float4 qv = qp4[rowg];
        float qx = qv.x * C1, qy = qv.y * C1, qz = qv.z * C1, qw = qv.w * C1;
        _Float16 hx = (_Float16)qx, hy = (_Float16)qy,
                 hz = (_Float16)qz, hw = (_Float16)qw;
        _Float16 gx = (_Float16)(qx - (float)hx), gy = (_Float16)(qy - (float)hy),
                 gz = (_Float16)(qz - (float)hz), gw = (_Float16)(qw - (float)hw);
        f16x8 a = {};
        if (quad == 0) {                                // hi half, duplicated j0-3/j4-7
            a[0] = hx; a[1] = hy; a[2] = hz; a[3] = hw;
            a[4] = hx; a[5] = hy; a[6] = hz; a[7] = hw;
        } else if (quad == 1) {                         // lo half, duplicated
            a[0] = gx; a[1] = gy; a[2] = gz; a[3] = gw;
            a[4] = gx; a[5] = gy; a[6] = gz; a[7] = gw;
        }
        afrag[s] = a;
    }
    bool okb = (quad < 2);
    __syncthreads();
    v2f ax2[2][2], ay2[2][2], az2[2][2], aw2[2][2], l2[2][2];
    #pragma unroll
    for (int s = 0; s < 2; s++)
        #pragma unroll
        for (int p = 0; p < 2; p++) {
            ax2[s][p] = (v2f)(0.f); ay2[s][p] = (v2f)(0.f);
            az2[s][p] = (v2f)(0.f); aw2[s][p] = (v2f)(0.f);
            l2[s][p]  = (v2f)(0.f);
        }
    const f16x8 bz = {};
    #pragma unroll 4
    for (int t = 0; t < 64; t++) {                      // 16-key tiles
        f16x8 kv8 = Kh2[t * 16 + c];                    // ds_read_b128 (broadcast)
        float4 vv = Vs[t * 16 + c];                     // ds_read_b128 (broadcast)
        f16x8 b = okb ? kv8 : bz;                       // quads 2-3 contribute zero
        v2f vx2 = (v2f){vv.x, vv.x}, vy2 = (v2f){vv.y, vv.y};
        v2f vz2 = (v2f){vv.z, vv.z}, vw2 = (v2f){vv.w, vv.w};
        #pragma unroll
        for (int s = 0; s < 2; s++) {
            f32x4 S = __builtin_amdgcn_mfma_f32_16x16x32_f16(afrag[s], b,
                                                             (f32x4)(0.f), 0, 0, 0);
            float p0 = __builtin_amdgcn_exp2f(S[0]);    // bare v_exp_f32 (trans pipe)
            float p1 = __builtin_amdgcn_exp2f(S[1]);
            float p2 = __builtin_amdgcn_exp2f(S[2]);
            float p3 = __builtin_amdgcn_exp2f(S[3]);
            v2f p01 = (v2f){p0, p1}, p23 = (v2f){p2, p3};
            l2[s][0] += p01; l2[s][1] += p23;           // v_pk_add_f32
            ax2[s][0] = __builtin_elementwise_fma(p01, vx2, ax2[s][0]);
            ax2[s][1] = __builtin_elementwise_fma(p23, vx2, ax2[s][1]);
            ay2[s][0] = __builtin_elementwise_fma(p01, vy2, ay2[s][0]);
            ay2[s][1] = __builtin_elementwise_fma(p23, vy2, ay2[s][1]);
            az2[s][0] = __builtin_elementwise_fma(p01, vz2, az2[s][0]);
            az2[s][1] = __builtin_elementwise_fma(p23, vz2, az2[s][1]);
            aw2[s][0] = __builtin_elementwise_fma(p01, vw2, aw2[s][0]);
            aw2[s][1] = __builtin_elementwise_fma(p23, vw2, aw2[s][1]);
        }
    }
    // LDS-reduction epilogue: per strip, each lane dumps its 4 rows x 1 key-column
    // partials; lanes 0..15 of each wave sum the 16 columns for one row each and
    // store the normalized o row. All accumulator state is in registers, so
    // aliasing red4/redl over Kh2/Vs after the barrier is safe.
    int b0 = bh >> 4, h = bh & 15;
    #pragma unroll
    for (int s = 0; s < 2; s++) {
        __syncthreads();                                // K/V reads (or prior strip) done
        #pragma unroll
        for (int r = 0; r < 4; r++) {
            int p = r >> 1; int hi = r & 1;
            int ix = w * 256 + (quad * 4 + r) * 16 + c; // per-wave 256-entry area
            float4 n4 = { hi ? ax2[s][p].y : ax2[s][p].x,
                          hi ? ay2[s][p].y : ay2[s][p].x,
                          hi ? az2[s][p].y : az2[s][p].x,
                          hi ? aw2[s][p].y : aw2[s][p].x };
            red4[ix] = n4;
            redl[ix] = hi ? l2[s][p].y : l2[s][p].x;
        }
        __syncthreads();
        if (lane < 16) {                                // one row per lane
            float4 acc = {0.f, 0.f, 0.f, 0.f}; float lacc = 0.f;
            #pragma unroll
            for (int cc = 0; cc < 16; cc++) {
                float4 t4 = red4[w * 256 + lane * 16 + cc];
                acc.x += t4.x; acc.y += t4.y; acc.z += t4.z; acc.w += t4.w;
                lacc += redl[w * 256 + lane * 16 + cc];
            }
            float rl = 1.f / lacc;
            int rowg = row0 + w * 32 + s * 16 + lane;
            float4 res = { acc.x * rl, acc.y * rl, acc.z * rl, acc.w * rl };
            *(float4*)&o[(b0 * 1024 + rowg) * 64 + h * 4] = res;
        }
    }
}

// ---------------- Kernel D: o @ w_proj + BN + max-unpool scatter ----------------
__global__ __launch_bounds__(256) void proj_kernel(const float* __restrict__ o,
                                                   const float* __restrict__ w_proj,
                                                   const float* __restrict__ gamma,
                                                   const float* __restrict__ beta,
                                                   const float* __restrict__ mean,
                                                   const float* __restrict__ var,
                                                   const int* __restrict__ idx,
                                                   float* __restrict__ out) {
    __shared__ float ws[64 * 64];                       // w_proj
    int b = blockIdx.x >> 5, hp = blockIdx.x & 31;
    int tid = threadIdx.x;
    for (int i = tid; i < 4096; i += 256) ws[i] = w_proj[i];
    int wp = tid & 31, cg = tid >> 5;                   // 8 c-groups x 32 wp
    float oreg[64];                                     // my o row in registers
    const float* orow = o + (b * 1024 + hp * 32 + wp) * 64;
    #pragma unroll
    for (int a4 = 0; a4 < 16; a4++) {
        float4 t4 = ((const float4*)orow)[a4];
        oreg[a4 * 4] = t4.x; oreg[a4 * 4 + 1] = t4.y;
        oreg[a4 * 4 + 2] = t4.z; oreg[a4 * 4 + 3] = t4.w;
    }
    __syncthreads();
    #pragma unroll
    for (int cc = 0; cc < 8; cc++) {
        int c = cg + 8 * cc;                            // 8 distinct banks -> conflict-free
        float acc = 0.f;
        #pragma unroll
        for (int a = 0; a < 64; a++) acc += oreg[a] * ws[a * 64 + c];
        float inv = gamma[c] * rsqrtf(var[c] + 1e-5f);
        float val = acc * inv + (beta[c] - mean[c] * inv);
        int id = idx[((b * 64 + c) * 32 + hp) * 32 + wp];
        int base = ((b * 64 + c) * 64 + 2 * hp) * 64 + 2 * wp;
        float2 r0 = { id == 0 ? val : 0.f, id == 1 ? val : 0.f };
        float2 r1 = { id == 2 ? val : 0.f, id == 3 ? val : 0.f };
        *(float2*)&out[base] = r0;                      // row 2hp,   cols 2wp..2wp+1
        *(float2*)&out[base + 64] = r1;                 // row 2hp+1
    }
}

extern "C" void kernel_launch(void* const* d_in, const int* in_sizes, int n_in,
                              void* d_out, int out_size, void* d_ws, size_t ws_size,
                              hipStream_t stream) {
    const float* x      = (const float*)d_in[0];
    const float* w_qkv  = (const float*)d_in[1];
    const float* w_proj = (const float*)d_in[2];
    const float* gamma  = (const float*)d_in[3];
    const float* beta   = (const float*)d_in[4];
    const float* bn_mean= (const float*)d_in[5];
    const float* bn_var = (const float*)d_in[6];
    float* out = (float*)d_out;

    const int SEG = 524288;                             // 8*1024*64
    float* ws = (float*)d_ws;
    float* t   = ws;
    int*   idx = (int*)(ws + SEG);
    float* q   = ws + 2 * SEG;
    float* k   = ws + 3 * SEG;
    float* v   = ws + 4 * SEG;
    float* o   = ws + 5 * SEG;

    pool_kernel<<<2048, 256, 0, stream>>>(x, t, idx);
    qkv_kernel<<<512, 192, 0, stream>>>(t, w_qkv, q, k, v);
    attn_kernel<<<1024, 256, 0, stream>>>(q, k, v, o);
    proj_kernel<<<256, 256, 0, stream>>>(o, w_proj, gamma, beta, bn_mean, bn_var, idx, out);
}

// Round 11
// 131.400 us; speedup vs baseline: 2.0194x; 1.0111x over previous
//
#include <hip/hip_runtime.h>
#include <hip/hip_bf16.h>

// Problem: B=8, C=DIM=64, H=W=64 -> pooled 32x32 (N=1024 tokens), 16 heads x d=4.
// ws layout (floats): t[524288] | idx[524288 ints] | q[524288] | k[524288] | v[524288]
//                     | o[524288] (normalized attention output, (B,N,64))
// q/k/v layout: (B, H=16, N=1024, D=4) contiguous -> per (b,h) a 4096-float slab.

typedef float    v2f   __attribute__((ext_vector_type(2)));
typedef float    f32x4 __attribute__((ext_vector_type(4)));
typedef _Float16 f16x8 __attribute__((ext_vector_type(8)));

// ---------------- Kernel A: 2x2 maxpool + argmax ----------------
__global__ __launch_bounds__(256) void pool_kernel(const float* __restrict__ x,
                                                   float* __restrict__ t,
                                                   int* __restrict__ idx) {
    int g = blockIdx.x * 256 + threadIdx.x;            // covers 8*64*32*32 = 524288
    int wp = g & 31, hp = (g >> 5) & 31, c = (g >> 10) & 63, b = g >> 16;
    const float* px = x + (((b * 64 + c) * 64 + 2 * hp) * 64 + 2 * wp);
    float2 r0 = *(const float2*)px;
    float2 r1 = *(const float2*)(px + 64);
    float best = r0.x; int bi = 0;                      // first-max semantics (strict >)
    if (r0.y > best) { best = r0.y; bi = 1; }
    if (r1.x > best) { best = r1.x; bi = 2; }
    if (r1.y > best) { best = r1.y; bi = 3; }
    int n = hp * 32 + wp;
    t[(b * 1024 + n) * 64 + c] = best;
    idx[g] = bi;                                        // layout (b,c,hp,wp)
}

// ---------------- Kernel B: qkv = t @ w_qkv, scatter to (B,H,N,4) ----------------
// R10 post-mortem: old version was LDS-return-bus-bound (256 broadcast b128 reads
// per thread = ~7.7 us/CU). Each thread now owns TWO columns {j, j+96} and 8 rows,
// halving block LDS reads (threads x rows x 16 = 24576 vs 49152). Each (row,col)
// is computed exactly once: tid and tid+96 share j but differ in row-half.
__global__ __launch_bounds__(192) void qkv_kernel(const float* __restrict__ t,
                                                  const float* __restrict__ w_qkv,
                                                  float* __restrict__ q,
                                                  float* __restrict__ k,
                                                  float* __restrict__ v) {
    __shared__ float trow[16 * 64];                     // 16 token rows
    int tid = threadIdx.x;                              // 0..191
    int row0 = blockIdx.x * 16;
    for (int i = tid; i < 1024; i += 192) trow[i] = t[row0 * 64 + i];
    int j  = tid % 96;                                  // my column pair {j, j+96}
    int rh = tid / 96;                                  // my row half (8 rows)
    float wc0[64], wc1[64];                             // two w_qkv columns in regs
    #pragma unroll
    for (int c = 0; c < 64; c++) {
        wc0[c] = w_qkv[c * 192 + j];
        wc1[c] = w_qkv[c * 192 + j + 96];
    }
    __syncthreads();
    int s0 = j >> 6, h0 = (j >> 2) & 15, d0 = j & 3;
    int j1 = j + 96;
    int s1 = j1 >> 6, h1 = (j1 >> 2) & 15, d1 = j1 & 3;
    float* dst0 = (s0 == 0) ? q : (s0 == 1) ? k : v;
    float* dst1 = (s1 == 0) ? q : (s1 == 1) ? k : v;
    for (int r = 0; r < 8; r++) {
        int row = rh * 8 + r;
        const float4* tr = (const float4*)&trow[row * 64];
        float a0 = 0.f, a1 = 0.f;
        #pragma unroll
        for (int c4 = 0; c4 < 16; c4++) {
            float4 tv = tr[c4];                         // <=2-way LDS broadcast: free
            a0 += tv.x * wc0[c4 * 4] + tv.y * wc0[c4 * 4 + 1]
                + tv.z * wc0[c4 * 4 + 2] + tv.w * wc0[c4 * 4 + 3];
            a1 += tv.x * wc1[c4 * 4] + tv.y * wc1[c4 * 4 + 1]
                + tv.z * wc1[c4 * 4 + 2] + tv.w * wc1[c4 * 4 + 3];
        }
        int ng = row0 + row, b = ng >> 10, n = ng & 1023;
        dst0[((b * 16 + h0) * 1024 + n) * 4 + d0] = a0;
        dst1[((b * 16 + h1) * 1024 + n) * 4 + d1] = a1;
    }
}

// ---------------- Kernel C: MFMA attention, Markidis-exact S, LDS epilogue ----------
// (unchanged from R10 -- passed validation + graph-replay re-validation)
//   A: quad0={qh|qh}, quad1={ql|ql}, quads2-3=0
//   B: quads0-1={kh[0..3]|kl[0..3]}, quads2-3=0
// S = (qh+ql)(kh+kl) -- exact to ~2^-22 relative.
// grid = 128 bh * 8 row-blocks of 128 rows; block = 4 waves, wave = 2 strips of 16.
__global__ __launch_bounds__(256) void attn_kernel(const float* __restrict__ q,
                                                   const float* __restrict__ k,
                                                   const float* __restrict__ v,
                                                   float* __restrict__ o) {
    __shared__ __align__(16) unsigned char smem[32768];
    f16x8*  Kh2  = (f16x8*)smem;                        // [0,16384): 1024 keys {hi4|lo4}
    float4* Vs   = (float4*)(smem + 16384);             // [16384,32768): 1024 vals fp32
    float4* red4 = (float4*)smem;                       // epilogue alias [0,16384)
    float*  redl = (float*)(smem + 16384);              // epilogue alias [16384,20480)
    int bh = blockIdx.x >> 3;
    int row0 = (blockIdx.x & 7) * 128;
    int tid = threadIdx.x;
    const float4* kp4 = (const float4*)(k + bh * 4096);
    const float4* vp4 = (const float4*)(v + bh * 4096);
    #pragma unroll
    for (int i = 0; i < 4; i++) {                       // stage K (hi/lo f16) + V (fp32)
        int ix = i * 256 + tid;
        float4 kf = kp4[ix];
        f16x8 kk;
        kk[0] = (_Float16)kf.x; kk[4] = (_Float16)(kf.x - (float)kk[0]);
        kk[1] = (_Float16)kf.y; kk[5] = (_Float16)(kf.y - (float)kk[1]);
        kk[2] = (_Float16)kf.z; kk[6] = (_Float16)(kf.z - (float)kk[2]);
        kk[3] = (_Float16)kf.w; kk[7] = (_Float16)(kf.w - (float)kk[3]);
        Kh2[ix] = kk;
        Vs[ix] = vp4[ix];
    }
    int w = tid >> 6, lane = tid & 63;
    int c = lane & 15, quad = lane >> 4;
    const float C1 = 0.5f * 1.44269504088896f;          // scale * log2(e), folded into Q
    const float4* qp4 = (const float4*)(q + bh * 4096);
    f16x8 afrag[2];
    #pragma unroll
    for (int s = 0; s < 2; s++) {                       // A-frags for my 2 row strips
        int rowg = row0 + w * 32 + s * 16 + c;
        float4 qv = qp4[rowg];
        float qx = qv.x * C1, qy = qv.y * C1, qz = qv.z * C1, qw = qv.w * C1;
        _Float16 hx = (_Float16)qx, hy = (_Float16)qy,
                 hz = (_Float16)qz, hw = (_Float16)qw;
        _Float16 gx = (_Float16)(qx - (float)hx), gy = (_Float16)(qy - (float)hy),
                 gz = (_Float16)(qz - (float)hz), gw = (_Float16)(qw - (float)hw);
        f16x8 a = {};
        if (quad == 0) {                                // hi half, duplicated j0-3/j4-7
            a[0] = hx; a[1] = hy; a[2] = hz; a[3] = hw;
            a[4] = hx; a[5] = hy; a[6] = hz; a[7] = hw;
        } else if (quad == 1) {                         // lo half, duplicated
            a[0] = gx; a[1] = gy; a[2] = gz; a[3] = gw;
            a[4] = gx; a[5] = gy; a[6] = gz; a[7] = gw;
        }
        afrag[s] = a;
    }
    bool okb = (quad < 2);
    __syncthreads();
    v2f ax2[2][2], ay2[2][2], az2[2][2], aw2[2][2], l2[2][2];
    #pragma unroll
    for (int s = 0; s < 2; s++)
        #pragma unroll
        for (int p = 0; p < 2; p++) {
            ax2[s][p] = (v2f)(0.f); ay2[s][p] = (v2f)(0.f);
            az2[s][p] = (v2f)(0.f); aw2[s][p] = (v2f)(0.f);
            l2[s][p]  = (v2f)(0.f);
        }
    const f16x8 bz = {};
    #pragma unroll 4
    for (int t = 0; t < 64; t++) {                      // 16-key tiles
        f16x8 kv8 = Kh2[t * 16 + c];                    // ds_read_b128 (broadcast)
        float4 vv = Vs[t * 16 + c];                     // ds_read_b128 (broadcast)
        f16x8 b = okb ? kv8 : bz;                       // quads 2-3 contribute zero
        v2f vx2 = (v2f){vv.x, vv.x}, vy2 = (v2f){vv.y, vv.y};
        v2f vz2 = (v2f){vv.z, vv.z}, vw2 = (v2f){vv.w, vv.w};
        #pragma unroll
        for (int s = 0; s < 2; s++) {
            f32x4 S = __builtin_amdgcn_mfma_f32_16x16x32_f16(afrag[s], b,
                                                             (f32x4)(0.f), 0, 0, 0);
            float p0 = __builtin_amdgcn_exp2f(S[0]);    // bare v_exp_f32 (trans pipe)
            float p1 = __builtin_amdgcn_exp2f(S[1]);
            float p2 = __builtin_amdgcn_exp2f(S[2]);
            float p3 = __builtin_amdgcn_exp2f(S[3]);
            v2f p01 = (v2f){p0, p1}, p23 = (v2f){p2, p3};
            l2[s][0] += p01; l2[s][1] += p23;           // v_pk_add_f32
            ax2[s][0] = __builtin_elementwise_fma(p01, vx2, ax2[s][0]);
            ax2[s][1] = __builtin_elementwise_fma(p23, vx2, ax2[s][1]);
            ay2[s][0] = __builtin_elementwise_fma(p01, vy2, ay2[s][0]);
            ay2[s][1] = __builtin_elementwise_fma(p23, vy2, ay2[s][1]);
            az2[s][0] = __builtin_elementwise_fma(p01, vz2, az2[s][0]);
            az2[s][1] = __builtin_elementwise_fma(p23, vz2, az2[s][1]);
            aw2[s][0] = __builtin_elementwise_fma(p01, vw2, aw2[s][0]);
            aw2[s][1] = __builtin_elementwise_fma(p23, vw2, aw2[s][1]);
        }
    }
    // LDS-reduction epilogue: per strip, each lane dumps its 4 rows x 1 key-column
    // partials; lanes 0..15 of each wave sum the 16 columns for one row each and
    // store the normalized o row.
    int b0 = bh >> 4, h = bh & 15;
    #pragma unroll
    for (int s = 0; s < 2; s++) {
        __syncthreads();                                // K/V reads (or prior strip) done
        #pragma unroll
        for (int r = 0; r < 4; r++) {
            int p = r >> 1; int hi = r & 1;
            int ix = w * 256 + (quad * 4 + r) * 16 + c; // per-wave 256-entry area
            float4 n4 = { hi ? ax2[s][p].y : ax2[s][p].x,
                          hi ? ay2[s][p].y : ay2[s][p].x,
                          hi ? az2[s][p].y : az2[s][p].x,
                          hi ? aw2[s][p].y : aw2[s][p].x };
            red4[ix] = n4;
            redl[ix] = hi ? l2[s][p].y : l2[s][p].x;
        }
        __syncthreads();
        if (lane < 16) {                                // one row per lane
            float4 acc = {0.f, 0.f, 0.f, 0.f}; float lacc = 0.f;
            #pragma unroll
            for (int cc = 0; cc < 16; cc++) {
                float4 t4 = red4[w * 256 + lane * 16 + cc];
                acc.x += t4.x; acc.y += t4.y; acc.z += t4.z; acc.w += t4.w;
                lacc += redl[w * 256 + lane * 16 + cc];
            }
            float rl = 1.f / lacc;
            int rowg = row0 + w * 32 + s * 16 + lane;
            float4 res = { acc.x * rl, acc.y * rl, acc.z * rl, acc.w * rl };
            *(float4*)&o[(b0 * 1024 + rowg) * 64 + h * 4] = res;
        }
    }
}

// ---------------- Kernel D: o @ w_proj + BN + max-unpool scatter ----------------
// R10 post-mortem: inner loop was 512 scalar ds_read_b32/thread. Channels now come
// in two groups of 4 CONSECUTIVE c so ws is read as float4 (128 ds_read_b128,
// 2 distinct addresses/wave = free broadcast). Global write pattern unchanged.
__global__ __launch_bounds__(256) void proj_kernel(const float* __restrict__ o,
                                                   const float* __restrict__ w_proj,
                                                   const float* __restrict__ gamma,
                                                   const float* __restrict__ beta,
                                                   const float* __restrict__ mean,
                                                   const float* __restrict__ var,
                                                   const int* __restrict__ idx,
                                                   float* __restrict__ out) {
    __shared__ float ws[64 * 64];                       // w_proj
    int b = blockIdx.x >> 5, hp = blockIdx.x & 31;
    int tid = threadIdx.x;
    for (int i = tid; i < 4096; i += 256) ws[i] = w_proj[i];
    int wp = tid & 31, cg = tid >> 5;                   // 8 c-groups x 32 wp
    float oreg[64];                                     // my o row in registers
    const float* orow = o + (b * 1024 + hp * 32 + wp) * 64;
    #pragma unroll
    for (int a4 = 0; a4 < 16; a4++) {
        float4 t4 = ((const float4*)orow)[a4];
        oreg[a4 * 4] = t4.x; oreg[a4 * 4 + 1] = t4.y;
        oreg[a4 * 4 + 2] = t4.z; oreg[a4 * 4 + 3] = t4.w;
    }
    __syncthreads();
    #pragma unroll
    for (int g = 0; g < 2; g++) {
        int c0 = cg * 8 + g * 4;                        // 4 consecutive channels
        float4 acc = {0.f, 0.f, 0.f, 0.f};
        #pragma unroll
        for (int a = 0; a < 64; a++) {
            float4 wv = *(const float4*)&ws[a * 64 + c0];   // b128, 2-addr broadcast
            acc.x += oreg[a] * wv.x; acc.y += oreg[a] * wv.y;
            acc.z += oreg[a] * wv.z; acc.w += oreg[a] * wv.w;
        }
        float accs[4] = { acc.x, acc.y, acc.z, acc.w };
        #pragma unroll
        for (int i = 0; i < 4; i++) {
            int c = c0 + i;
            float inv = gamma[c] * rsqrtf(var[c] + 1e-5f);
            float val = accs[i] * inv + (beta[c] - mean[c] * inv);
            int id = idx[((b * 64 + c) * 32 + hp) * 32 + wp];
            int base = ((b * 64 + c) * 64 + 2 * hp) * 64 + 2 * wp;
            float2 r0 = { id == 0 ? val : 0.f, id == 1 ? val : 0.f };
            float2 r1 = { id == 2 ? val : 0.f, id == 3 ? val : 0.f };
            *(float2*)&out[base] = r0;                  // row 2hp,   cols 2wp..2wp+1
            *(float2*)&out[base + 64] = r1;             // row 2hp+1
        }
    }
}

extern "C" void kernel_launch(void* const* d_in, const int* in_sizes, int n_in,
                              void* d_out, int out_size, void* d_ws, size_t ws_size,
                              hipStream_t stream) {
    const float* x      = (const float*)d_in[0];
    const float* w_qkv  = (const float*)d_in[1];
    const float* w_proj = (const float*)d_in[2];
    const float* gamma  = (const float*)d_in[3];
    const float* beta   = (const float*)d_in[4];
    const float* bn_mean= (const float*)d_in[5];
    const float* bn_var = (const float*)d_in[6];
    float* out = (float*)d_out;

    const int SEG = 524288;                             // 8*1024*64
    float* ws = (float*)d_ws;
    float* t   = ws;
    int*   idx = (int*)(ws + SEG);
    float* q   = ws + 2 * SEG;
    float* k   = ws + 3 * SEG;
    float* v   = ws + 4 * SEG;
    float* o   = ws + 5 * SEG;

    pool_kernel<<<2048, 256, 0, stream>>>(x, t, idx);
    qkv_kernel<<<512, 192, 0, stream>>>(t, w_qkv, q, k, v);
    attn_kernel<<<1024, 256, 0, stream>>>(q, k, v, o);
    proj_kernel<<<256, 256, 0, stream>>>(o, w_proj, gamma, beta, bn_mean, bn_var, idx, out);
}